// Round 2
// baseline (533.326 us; speedup 1.0000x reference)
//
#include <hip/hip_runtime.h>
#include <hip/hip_bf16.h>
#include <math.h>

// Problem constants
#define BB 8
#define LL 8192
#define DD 512
#define NROWS (BB * LL)  // 65536

// d_out layout (floats)
#define OUT_COMP   0
#define OUT_MASK   33554432
#define OUT_BHARD  33619968
#define OUT_P      33685504
#define OUT_PCOMP  33751040
#define OUT_LOSS   33816576

// ws layout (bytes)
#define WS_FIXLIST 0         // 65536*4
#define WS_FIXCNT  262144    // 4
#define WS_COUNTS  262148    // 32
#define WS_SUMP    262180    // 32
#define WS_SEL     262212    // 65536*4 -> 524356
#define WS_SSK     524416    // 65536*4
#define WS_SSQ     786560    // 65536*4
#define WS_DOT     1048704   // 65536*4
#define WS_WQH     1310848   // 512 KB each
#define WS_WKH     1835136   // end ~2.4 MB

#define FIX_CAP 65536
// widened: 2-pairing GEMM adds ~2e-5 sd cos error; 4e-4 = ~17 sigma flip margin
#define FIX_TAU 4e-4f

typedef __attribute__((ext_vector_type(8))) _Float16 half8;
typedef __attribute__((ext_vector_type(4))) float f32x4;

// async global->LDS, 16 B per lane; lds base wave-uniform, data lands at
// lds + lane*16 (m104/m108) -- layouts below are lane-sequential.
static __device__ __forceinline__ void ld_g2l16(const void* g, void* l) {
  __builtin_amdgcn_global_load_lds(
      (const __attribute__((address_space(1))) void*)g,
      (__attribute__((address_space(3))) void*)l, 16, 0, 0);
}

// ---------------------------------------------------------------------------
// Pass 0: split Wq,Wk into f16 hi (lo no longer used: 2-pairing GEMM),
// fragment-chunk order: chunk c = (kt*32 + ct)*64 + kblk*16 + n holds
// W[e = ct*16+n][d = kt*32 + kblk*8 .. +8]. Also zero-inits accumulators.
// ---------------------------------------------------------------------------
__global__ __launch_bounds__(256) void wsplit(
    const float* __restrict__ Wq, const float* __restrict__ Wk,
    _Float16* __restrict__ wqh, _Float16* __restrict__ wkh,
    float* __restrict__ ssk, float* __restrict__ ssq,
    float* __restrict__ dotb, int* __restrict__ fixcnt) {
  const int t = blockIdx.x * 256 + threadIdx.x;  // 0..65535
  if (t == 0) *fixcnt = 0;
  ssk[t] = 0.0f;
  ssq[t] = 0.0f;
  dotb[t] = 0.0f;

  const int m = t >> 15;         // 0 = Wq, 1 = Wk
  const int c = t & 32767;       // chunk id
  const int kt = c >> 11;
  const int ct = (c >> 6) & 31;
  const int l = c & 63;
  const int n = l & 15;
  const int kblk = l >> 4;
  const int e = ct * 16 + n;
  const int d0 = kt * 32 + kblk * 8;
  const float* src = (m ? Wk : Wq) + (long)e * 512 + d0;
  _Float16* dh = (m ? wkh : wqh) + (long)c * 8;
  float4 v0 = *(const float4*)src;
  float4 v1 = *(const float4*)(src + 4);
  float av[8] = {v0.x, v0.y, v0.z, v0.w, v1.x, v1.y, v1.z, v1.w};
  half8 hi;
#pragma unroll
  for (int j = 0; j < 8; ++j) hi[j] = (_Float16)av[j];
  *(half8*)dh = hi;
}

// ---------------------------------------------------------------------------
// FUSED GEMM: q = x*Wq^T and k = x*Wk^T in one pass. 128x128 tile, BK=32,
// 4 waves 2x2. 2-pairing f16 split (ah*bh + al*bh; B hi-only — residual
// ~2e-5 in cos, covered by widened-tau f64 fixup).
// Full LDS double-buffer (A+B, 2x32KB) + 2-ahead A-reg prefetch -> ONE
// barrier per K-step; B g2l for kt+1 flies under kt's 256 MFMAs.
// XCD-swizzled blockIdx so the 4 cb-siblings of an rb share L2 A-panels.
// ---------------------------------------------------------------------------
__global__ __launch_bounds__(256, 2) void gemm_fused(
    const float* __restrict__ x,
    const _Float16* __restrict__ wqh, const _Float16* __restrict__ wkh,
    float* __restrict__ ssqOut, float* __restrict__ sskOut,
    float* __restrict__ dotOut,
    float* __restrict__ qedge, float* __restrict__ kedge) {
  __shared__ _Float16 smem[32768];  // 64 KB: two 32 KB buffers
  // per-buffer layout (halfs): AH +0, AL +4096, BQH +8192, BKH +12288
  _Float16* AH0 = smem;
  _Float16* AL0 = smem + 4096;
  _Float16* BQ0 = smem + 8192;
  _Float16* BK0 = smem + 12288;
  _Float16* AH1 = smem + 16384;
  _Float16* AL1 = smem + 20480;
  _Float16* BQ1 = smem + 24576;
  _Float16* BK1 = smem + 28672;

  const int tid = threadIdx.x;
  const int lane = tid & 63;
  const int w = tid >> 6;
  const int wrow = w & 1, wcol = w >> 1;
  const int g = lane >> 4, n = lane & 15;
  const int bx0 = blockIdx.x;
  const int bx = ((bx0 & 7) << 8) | (bx0 >> 3);  // XCD-contiguous (2048 = 8*256)
  const int rb = bx >> 2, cb = bx & 3;
  const long r0 = (long)rb * 128;

  // A staging: tid = (mbs<<6)|(kblk<<4)|ms -> chunk c1=tid (row arow),
  // chunk c2=tid+256 (row arow+64). 8 consecutive floats at col akb*8.
  const int arow = ((tid >> 6) << 4) | (tid & 15);
  const int akb = (tid >> 4) & 3;
  const float* ap = x + (r0 + arow) * 512 + akb * 8;

  f32x4 accq[4][4], acck[4][4];
#pragma unroll
  for (int mb = 0; mb < 4; ++mb)
#pragma unroll
    for (int nb = 0; nb < 4; ++nb) {
      accq[mb][nb] = (f32x4){0.f, 0.f, 0.f, 0.f};
      acck[mb][nb] = (f32x4){0.f, 0.f, 0.f, 0.f};
    }

#define STAGE_B(ktv, BQ_, BK_)                                            \
  do {                                                                    \
    const long bb = ((long)((ktv)*32 + cb * 8) << 9) + w * 1024 + lane * 8; \
    ld_g2l16(wqh + bb, (BQ_) + w * 1024);                                 \
    ld_g2l16(wqh + bb + 512, (BQ_) + w * 1024 + 512);                     \
    ld_g2l16(wkh + bb, (BK_) + w * 1024);                                 \
    ld_g2l16(wkh + bb + 512, (BK_) + w * 1024 + 512);                     \
  } while (0)

#define CONV_A(F0, F1, F2, F3, AH_, AL_)                                  \
  do {                                                                    \
    float av0[8] = {F0.x, F0.y, F0.z, F0.w, F1.x, F1.y, F1.z, F1.w};      \
    float av1[8] = {F2.x, F2.y, F2.z, F2.w, F3.x, F3.y, F3.z, F3.w};      \
    half8 h0, h1, l0, l1;                                                 \
    _Pragma("unroll") for (int j = 0; j < 8; ++j) {                       \
      _Float16 a = (_Float16)av0[j];                                      \
      h0[j] = a;                                                          \
      l0[j] = (_Float16)(av0[j] - (float)a);                              \
      _Float16 b = (_Float16)av1[j];                                      \
      h1[j] = b;                                                          \
      l1[j] = (_Float16)(av1[j] - (float)b);                              \
    }                                                                     \
    *(half8*)((AH_) + tid * 8) = h0;                                      \
    *(half8*)((AH_) + (tid + 256) * 8) = h1;                              \
    *(half8*)((AL_) + tid * 8) = l0;                                      \
    *(half8*)((AL_) + (tid + 256) * 8) = l1;                              \
  } while (0)

#define COMPUTE(AH_, AL_, BQ_, BK_)                                       \
  do {                                                                    \
    half8 ah[4], al[4], bq[4], bk[4];                                     \
    _Pragma("unroll") for (int mb = 0; mb < 4; ++mb) {                    \
      const int cm = wrow * 4 + mb;                                       \
      ah[mb] = *(const half8*)((AH_) + (cm * 64 + lane) * 8);             \
      al[mb] = *(const half8*)((AL_) + (cm * 64 + lane) * 8);             \
    }                                                                     \
    _Pragma("unroll") for (int nb = 0; nb < 4; ++nb) {                    \
      bq[nb] = *(const half8*)((BQ_) + ((wcol * 4 + nb) * 64 + lane) * 8);\
      bk[nb] = *(const half8*)((BK_) + ((wcol * 4 + nb) * 64 + lane) * 8);\
    }                                                                     \
    __builtin_amdgcn_s_setprio(1);                                        \
    _Pragma("unroll") for (int nb = 0; nb < 4; ++nb)                      \
        _Pragma("unroll") for (int mb = 0; mb < 4; ++mb) {                \
      accq[mb][nb] = __builtin_amdgcn_mfma_f32_16x16x32_f16(              \
          ah[mb], bq[nb], accq[mb][nb], 0, 0, 0);                         \
      acck[mb][nb] = __builtin_amdgcn_mfma_f32_16x16x32_f16(              \
          ah[mb], bk[nb], acck[mb][nb], 0, 0, 0);                         \
      accq[mb][nb] = __builtin_amdgcn_mfma_f32_16x16x32_f16(              \
          al[mb], bq[nb], accq[mb][nb], 0, 0, 0);                         \
      acck[mb][nb] = __builtin_amdgcn_mfma_f32_16x16x32_f16(              \
          al[mb], bk[nb], acck[mb][nb], 0, 0, 0);                         \
    }                                                                     \
    __builtin_amdgcn_s_setprio(0);                                        \
  } while (0)

  // ---- prologue: tile 0 into buf0, prefetch A(1) regs ----
  STAGE_B(0, BQ0, BK0);
  float4 pa0 = *(const float4*)(ap);
  float4 pa1 = *(const float4*)(ap + 4);
  float4 pa2 = *(const float4*)(ap + 64 * 512);
  float4 pa3 = *(const float4*)(ap + 64 * 512 + 4);
  CONV_A(pa0, pa1, pa2, pa3, AH0, AL0);
  float4 pb0 = *(const float4*)(ap + 32);
  float4 pb1 = *(const float4*)(ap + 32 + 4);
  float4 pb2 = *(const float4*)(ap + 32 + 64 * 512);
  float4 pb3 = *(const float4*)(ap + 32 + 64 * 512 + 4);
  __syncthreads();

  for (int i = 0; i < 8; ++i) {
    const int kt = 2 * i;
    // ---- even step: compute buf0(kt), stage buf1(kt+1) ----
    STAGE_B(kt + 1, BQ1, BK1);
    CONV_A(pb0, pb1, pb2, pb3, AH1, AL1);
    if (i < 7) {
      const float* xp = ap + (kt + 2) * 32;
      pa0 = *(const float4*)(xp);
      pa1 = *(const float4*)(xp + 4);
      pa2 = *(const float4*)(xp + 64 * 512);
      pa3 = *(const float4*)(xp + 64 * 512 + 4);
    }
    COMPUTE(AH0, AL0, BQ0, BK0);
    __syncthreads();
    // ---- odd step: compute buf1(kt+1), stage buf0(kt+2) ----
    if (i < 7) {
      STAGE_B(kt + 2, BQ0, BK0);
      CONV_A(pa0, pa1, pa2, pa3, AH0, AL0);
      const float* xp2 = ap + (kt + 3) * 32;
      pb0 = *(const float4*)(xp2);
      pb1 = *(const float4*)(xp2 + 4);
      pb2 = *(const float4*)(xp2 + 64 * 512);
      pb3 = *(const float4*)(xp2 + 64 * 512 + 4);
    }
    COMPUTE(AH1, AL1, BQ1, BK1);
    __syncthreads();
  }

  // ---------------- epilogue ----------------
  // k-acc -> LDS (f16), row-major stride 136 halfs (=272 B) so the 4 g-rows
  // of a read/write group land on different banks. 128*136*2 B = 34 KB.
  _Float16* KX = smem;
  const int col0 = wcol * 64 + n;
  const int rbase = wrow * 64;
#pragma unroll
  for (int mb = 0; mb < 4; ++mb)
#pragma unroll
    for (int reg = 0; reg < 4; ++reg) {
      const int rl = rbase + mb * 16 + g * 4 + reg;
#pragma unroll
      for (int nb = 0; nb < 4; ++nb)
        KX[rl * 136 + col0 + nb * 16] = (_Float16)acck[mb][nb][reg];
    }
  __syncthreads();

  // block-boundary edges: k local row 127 and q local row 0 (f32, 128 cols
  // per (rb,cb) block -> full 512 cols per rb across cb).
  if (wrow == 1 && g == 3) {
#pragma unroll
    for (int nb = 0; nb < 4; ++nb)
      kedge[rb * 512 + cb * 128 + col0 + nb * 16] = acck[3][nb][3];
  }
  if (wrow == 0 && g == 0) {
#pragma unroll
    for (int nb = 0; nb < 4; ++nb)
      qedge[rb * 512 + cb * 128 + col0 + nb * 16] = accq[0][nb][0];
  }

  // per-row partials: ssq, ssk, dot = q[r] . k[r-1] (k from LDS, f16).
  // Local row 0's dot comes from edgedot.
#pragma unroll
  for (int mb = 0; mb < 4; ++mb) {
#pragma unroll
    for (int reg = 0; reg < 4; ++reg) {
      const int rl = rbase + mb * 16 + g * 4 + reg;
      const long row = r0 + rl;
      float sq = 0.f, sk = 0.f, dt = 0.f;
#pragma unroll
      for (int nb = 0; nb < 4; ++nb) {
        float qv = accq[mb][nb][reg];
        float kv = acck[mb][nb][reg];
        sq = fmaf(qv, qv, sq);
        sk = fmaf(kv, kv, sk);
        if (rl > 0) {
          float kp = (float)KX[(rl - 1) * 136 + col0 + nb * 16];
          dt = fmaf(qv, kp, dt);
        }
      }
#pragma unroll
      for (int m = 1; m < 16; m <<= 1) {
        sq += __shfl_xor(sq, m, 64);
        sk += __shfl_xor(sk, m, 64);
        dt += __shfl_xor(dt, m, 64);
      }
      if (n == 0) {
        atomicAdd(&ssqOut[row], sq);
        atomicAdd(&sskOut[row], sk);
        if (rl > 0) atomicAdd(&dotOut[row], dt);
      }
    }
  }
#undef STAGE_B
#undef CONV_A
#undef COMPUTE
}

// ---------------------------------------------------------------------------
// Boundary rows (r multiple of 128, r's l != 0): dot = qedge[rb] . kedge[rb-1]
// over all 512 cols. Sole writer of dotOut for these rows.
// ---------------------------------------------------------------------------
__global__ __launch_bounds__(64) void edgedot(
    const float* __restrict__ qedge, const float* __restrict__ kedge,
    float* __restrict__ dotOut) {
  const int rb = blockIdx.x;  // 0..511
  if (rb == 0) return;
  const long row = (long)rb * 128;
  if ((row & (LL - 1)) == 0) return;  // l == 0: p forced to 1, dot unused
  const int lane = threadIdx.x;
  float dt = 0.f;
#pragma unroll
  for (int c = lane; c < 512; c += 64)
    dt = fmaf(qedge[rb * 512 + c], kedge[(rb - 1) * 512 + c], dt);
#pragma unroll
  for (int m = 1; m < 64; m <<= 1) dt += __shfl_xor(dt, m, 64);
  if (lane == 0) dotOut[row] = dt;
}

// ---------------------------------------------------------------------------
// Combine: cos from partials -> p, b_hard, fixlist.
// ---------------------------------------------------------------------------
__global__ __launch_bounds__(256) void combine(
    const float* __restrict__ ssq, const float* __restrict__ ssk,
    const float* __restrict__ dotb, float* __restrict__ dout,
    int* __restrict__ fixlist, int* __restrict__ fixcnt) {
  const int r = blockIdx.x * 256 + threadIdx.x;
  const int l = r & (LL - 1);
  float p;
  float cosv = 0.0f;
  if (l != 0) {
    float nq = fmaxf(sqrtf(ssq[r]), 1e-12f);
    float nk = fmaxf(sqrtf(ssk[r - 1]), 1e-12f);
    cosv = dotb[r] / (nq * nk);
    p = fminf(fmaxf(0.5f * (1.0f - cosv), 0.0f), 1.0f);
  } else {
    p = 1.0f;
  }
  dout[OUT_P + r] = p;
  dout[OUT_BHARD + r] = (p >= 0.5f) ? 1.0f : 0.0f;
  if (l != 0 && fabsf(cosv) < FIX_TAU) {
    int idx = atomicAdd(fixcnt, 1);
    if (idx < FIX_CAP) fixlist[idx] = r;
  }
}

// ---------------------------------------------------------------------------
// f64 recompute of borderline rows (expected ~500 rows at TAU=4e-4).
// ---------------------------------------------------------------------------
__global__ __launch_bounds__(256) void fixup(
    const float* __restrict__ x, const float* __restrict__ Wq,
    const float* __restrict__ Wk, float* __restrict__ dout,
    const int* __restrict__ fixlist, const int* __restrict__ fixcnt) {
  __shared__ float xr[512], xp[512];
  __shared__ double red[3][256];
  const int t = threadIdx.x;
  int nfix = *fixcnt;
  if (nfix > FIX_CAP) nfix = FIX_CAP;

  for (int idx = blockIdx.x; idx < nfix; idx += gridDim.x) {
    const int r = fixlist[idx];
    for (int d = t; d < 512; d += 256) {
      xr[d] = x[(long)r * 512 + d];
      xp[d] = x[(long)(r - 1) * 512 + d];
    }
    __syncthreads();
    double ssq = 0.0, ssk = 0.0, dot = 0.0;
    for (int e = t; e < 512; e += 256) {
      const float* wq = Wq + (long)e * 512;
      const float* wk = Wk + (long)e * 512;
      double q = 0.0, k = 0.0;
      for (int d = 0; d < 512; ++d) {
        q = fma((double)xr[d], (double)wq[d], q);
        k = fma((double)xp[d], (double)wk[d], k);
      }
      ssq += q * q;
      ssk += k * k;
      dot += q * k;
    }
    red[0][t] = ssq;
    red[1][t] = ssk;
    red[2][t] = dot;
    __syncthreads();
    for (int s = 128; s > 0; s >>= 1) {
      if (t < s) {
        red[0][t] += red[0][t + s];
        red[1][t] += red[1][t + s];
        red[2][t] += red[2][t + s];
      }
      __syncthreads();
    }
    if (t == 0) {
      double nq = sqrt(red[0][0]);
      double nk = sqrt(red[1][0]);
      if (nq < 1e-12) nq = 1e-12;
      if (nk < 1e-12) nk = 1e-12;
      float c = (float)(red[2][0] / (nq * nk));
      float p = fminf(fmaxf(0.5f * (1.0f - c), 0.0f), 1.0f);
      dout[OUT_P + r] = p;
      dout[OUT_BHARD + r] = (p >= 0.5f) ? 1.0f : 0.0f;
    }
    __syncthreads();
  }
}

// ---------------------------------------------------------------------------
// Per-batch scan (shfl-based), mask, p_compressed, sel, counts.
// ---------------------------------------------------------------------------
__global__ __launch_bounds__(256) void scanb(
    float* __restrict__ dout, int* __restrict__ sel,
    int* __restrict__ counts, float* __restrict__ sump) {
  __shared__ int wtot[4];
  __shared__ float wps[4];
  const int b = blockIdx.x;
  const int t = threadIdx.x;
  const int lane = t & 63, wv = t >> 6;
  const long base = (long)b * LL;

  int cnt = 0;
  float psum = 0.0f;
#pragma unroll 4
  for (int j = 0; j < 32; ++j) {
    int l = t * 32 + j;
    float bh = dout[OUT_BHARD + base + l];
    float pv = dout[OUT_P + base + l];
    cnt += (bh > 0.5f) ? 1 : 0;
    psum += pv;
  }
  int inc = cnt;
#pragma unroll
  for (int off = 1; off < 64; off <<= 1) {
    int u = __shfl_up(inc, off, 64);
    if (lane >= off) inc += u;
  }
  float ps = psum;
#pragma unroll
  for (int off = 1; off < 64; off <<= 1) ps += __shfl_xor(ps, off, 64);
  if (lane == 63) wtot[wv] = inc;
  if (lane == 0) wps[wv] = ps;
  __syncthreads();
  int wbase = 0, total = 0;
#pragma unroll
  for (int i = 0; i < 4; ++i) {
    int c = wtot[i];
    if (i < wv) wbase += c;
    total += c;
  }
  if (t == 0) {
    counts[b] = total;
    sump[b] = wps[0] + wps[1] + wps[2] + wps[3];
  }
  for (int j = 0; j < 32; ++j) {
    int l = t * 32 + j;
    dout[OUT_MASK + base + l] = (l < total) ? 1.0f : 0.0f;
    dout[OUT_PCOMP + base + l] = 0.0f;
  }
  __syncthreads();
  int pos = wbase + inc - cnt;  // exclusive prefix
  for (int j = 0; j < 32; ++j) {
    int l = t * 32 + j;
    float bh = dout[OUT_BHARD + base + l];
    if (bh > 0.5f) {
      dout[OUT_PCOMP + base + pos] = dout[OUT_P + base + l];
      sel[base + pos] = l;
      ++pos;
    }
  }
}

// ---------------------------------------------------------------------------
__global__ void lossk(float* __restrict__ dout, const int* __restrict__ counts,
                      const float* __restrict__ sump) {
  if (threadIdx.x == 0 && blockIdx.x == 0) {
    float fc = 0.0f, gs = 0.0f;
    for (int b = 0; b < BB; ++b) {
      fc += (float)counts[b];
      gs += sump[b];
    }
    float F = fc / (float)NROWS;
    float G = gs / (float)NROWS;
    dout[OUT_LOSS] = 1.2f * (5.0f * F * G + (1.0f - F) * (1.0f - G));
  }
}

// ---------------------------------------------------------------------------
__global__ __launch_bounds__(128) void emit(
    const float* __restrict__ x, float* __restrict__ dout,
    const int* __restrict__ sel, const int* __restrict__ counts) {
  const long bid = blockIdx.x;
  const int b = (int)(bid >> 13);
  const int j = (int)(bid & (LL - 1));
  const int cnt = counts[b];
  float4 v = make_float4(0.0f, 0.0f, 0.0f, 0.0f);
  if (j < cnt) {
    const int l = sel[((long)b << 13) + j];
    v = *(const float4*)(x + (((long)b << 13) + l) * 512 + threadIdx.x * 4);
  }
  *(float4*)(dout + OUT_COMP + (((long)b << 13) + j) * 512 + threadIdx.x * 4) = v;
}

// ---------------------------------------------------------------------------
extern "C" void kernel_launch(void* const* d_in, const int* in_sizes, int n_in,
                              void* d_out, int out_size, void* d_ws,
                              size_t ws_size, hipStream_t stream) {
  const float* x = (const float*)d_in[0];
  const float* Wq = (const float*)d_in[1];
  const float* Wk = (const float*)d_in[2];
  float* out = (float*)d_out;
  char* ws = (char*)d_ws;

  int* fixlist = (int*)(ws + WS_FIXLIST);
  int* fixcnt = (int*)(ws + WS_FIXCNT);
  int* counts = (int*)(ws + WS_COUNTS);
  float* sump = (float*)(ws + WS_SUMP);
  int* sel = (int*)(ws + WS_SEL);
  float* ssk = (float*)(ws + WS_SSK);
  float* ssq = (float*)(ws + WS_SSQ);
  float* dotb = (float*)(ws + WS_DOT);
  _Float16* wqh = (_Float16*)(ws + WS_WQH);
  _Float16* wkh = (_Float16*)(ws + WS_WKH);

  // edge buffers (512x512 f32 each = 1 MB) staged in d_out's compressed
  // region; emit overwrites it at the end.
  float* kedge = (float*)(out + OUT_COMP);
  float* qedge = (float*)(out + OUT_COMP + 262144);

  wsplit<<<256, 256, 0, stream>>>(Wq, Wk, wqh, wkh, ssk, ssq, dotb, fixcnt);
  gemm_fused<<<2048, 256, 0, stream>>>(x, wqh, wkh, ssq, ssk, dotb, qedge, kedge);
  edgedot<<<512, 64, 0, stream>>>(qedge, kedge, dotb);
  combine<<<NROWS / 256, 256, 0, stream>>>(ssq, ssk, dotb, out, fixlist, fixcnt);
  fixup<<<512, 256, 0, stream>>>(x, Wq, Wk, out, fixlist, fixcnt);
  scanb<<<BB, 256, 0, stream>>>(out, sel, counts, sump);
  lossk<<<1, 64, 0, stream>>>(out, counts, sump);
  emit<<<NROWS, 128, 0, stream>>>(x, out, sel, counts);
}

// Round 3
// 487.217 us; speedup vs baseline: 1.0946x; 1.0946x over previous
//
#include <hip/hip_runtime.h>
#include <hip/hip_bf16.h>
#include <math.h>

// Problem constants
#define BB 8
#define LL 8192
#define DD 512
#define NROWS (BB * LL)  // 65536

// d_out layout (floats)
#define OUT_COMP   0
#define OUT_MASK   33554432
#define OUT_BHARD  33619968
#define OUT_P      33685504
#define OUT_PCOMP  33751040
#define OUT_LOSS   33816576

// ws layout (bytes)
#define WS_FIXLIST 0         // 65536*4
#define WS_FIXCNT  262144    // 4
#define WS_COUNTS  262148    // 32
#define WS_SUMP    262180    // 32
#define WS_SEL     262212    // 65536*4 -> 524356
#define WS_SSK     524416    // 65536*4
#define WS_SSQ     786560    // 65536*4
#define WS_DOT     1048704   // 65536*4
#define WS_WQH     1310848   // 512 KB each
#define WS_WKH     1835136   // end ~2.4 MB

#define FIX_CAP 65536
// 2-pairing cos error rms ~2e-6 (dropped al*bl term is ~5e-8); 1e-4 = 50 sigma
#define FIX_TAU 1e-4f

typedef __attribute__((ext_vector_type(8))) _Float16 half8;
typedef __attribute__((ext_vector_type(4))) float f32x4;

// raw barrier: drain LDS ops only (ds_write A visibility); global loads are
// all register-destined and may stay in flight across the barrier.
#define BARRIER()                                          \
  do {                                                     \
    asm volatile("s_waitcnt lgkmcnt(0)" ::: "memory");     \
    __builtin_amdgcn_sched_barrier(0);                     \
    __builtin_amdgcn_s_barrier();                          \
  } while (0)

// ---------------------------------------------------------------------------
// Pass 0: split Wq,Wk into f16 hi (2-pairing GEMM: A hi/lo x B hi),
// fragment-chunk order: chunk c = (kt*32 + ct)*64 + kblk*16 + n holds
// W[e = ct*16+n][d = kt*32 + kblk*8 .. +8]. Also zero-inits accumulators.
// This order makes a lane's B-fragment a contiguous 16 B global load.
// ---------------------------------------------------------------------------
__global__ __launch_bounds__(256) void wsplit(
    const float* __restrict__ Wq, const float* __restrict__ Wk,
    _Float16* __restrict__ wqh, _Float16* __restrict__ wkh,
    float* __restrict__ ssk, float* __restrict__ ssq,
    float* __restrict__ dotb, int* __restrict__ fixcnt) {
  const int t = blockIdx.x * 256 + threadIdx.x;  // 0..65535
  if (t == 0) *fixcnt = 0;
  ssk[t] = 0.0f;
  ssq[t] = 0.0f;
  dotb[t] = 0.0f;

  const int m = t >> 15;         // 0 = Wq, 1 = Wk
  const int c = t & 32767;       // chunk id
  const int kt = c >> 11;
  const int ct = (c >> 6) & 31;
  const int l = c & 63;
  const int n = l & 15;
  const int kblk = l >> 4;
  const int e = ct * 16 + n;
  const int d0 = kt * 32 + kblk * 8;
  const float* src = (m ? Wk : Wq) + (long)e * 512 + d0;
  _Float16* dh = (m ? wkh : wqh) + (long)c * 8;
  float4 v0 = *(const float4*)src;
  float4 v1 = *(const float4*)(src + 4);
  float av[8] = {v0.x, v0.y, v0.z, v0.w, v1.x, v1.y, v1.z, v1.w};
  half8 hi;
#pragma unroll
  for (int j = 0; j < 8; ++j) hi[j] = (_Float16)av[j];
  *(half8*)dh = hi;
}

// ---------------------------------------------------------------------------
// FUSED GEMM: q = x*Wq^T and k = x*Wk^T in one pass. 128x128 tile, BK=32,
// 4 waves 2x2. 2-pairing f16 split (ah*bh + al*bh).
// B NEVER touches LDS: wqh/wkh are in fragment-chunk order, so each lane's
// B fragment is one coalesced global_load_dwordx4, L2-resident (1 MB shared
// by all 512 rb-blocks). LDS holds only A (hi/lo, double-buffered, 32 KB).
// Barrier drains lgkmcnt only -- global loads stay in flight across it.
// XCD-swizzled blockIdx so the 4 cb-siblings of an rb share L2 A-panels.
// ---------------------------------------------------------------------------
__global__ __launch_bounds__(256, 2) void gemm_fused(
    const float* __restrict__ x,
    const _Float16* __restrict__ wqh, const _Float16* __restrict__ wkh,
    float* __restrict__ ssqOut, float* __restrict__ sskOut,
    float* __restrict__ dotOut,
    float* __restrict__ qedge, float* __restrict__ kedge) {
  __shared__ _Float16 smem[17408];  // 34 KB (epilogue KX = 128*136 halfs)
  _Float16* AH0 = smem;             // chunks: (mbs*64 + kblk*16 + ms)
  _Float16* AL0 = smem + 4096;
  _Float16* AH1 = smem + 8192;
  _Float16* AL1 = smem + 12288;

  const int tid = threadIdx.x;
  const int lane = tid & 63;
  const int w = tid >> 6;
  const int wrow = w & 1, wcol = w >> 1;
  const int g = lane >> 4, n = lane & 15;
  const int bx0 = blockIdx.x;
  const int bx = ((bx0 & 7) << 8) | (bx0 >> 3);  // XCD-contiguous (2048 = 8*256)
  const int rb = bx >> 2, cb = bx & 3;
  const long r0 = (long)rb * 128;

  // A staging: tid = (mbs<<6)|(kblk<<4)|ms -> chunk c1=tid (row arow),
  // chunk c2=tid+256 (row arow+64). 8 consecutive floats at col akb*8.
  const int arow = ((tid >> 6) << 4) | (tid & 15);
  const int akb = (tid >> 4) & 3;
  const float* ap = x + (r0 + arow) * 512 + akb * 8;

  // B fragment bases (global, fragment-chunk order): lane reads 16 B at
  // chunk ((kt*32 + cb*8 + wcol*4 + nb)*64 + lane); per-kt stride 16384 halfs.
  const _Float16* bqb = wqh + ((long)((cb * 8 + wcol * 4) * 64 + lane)) * 8;
  const _Float16* bkb = wkh + ((long)((cb * 8 + wcol * 4) * 64 + lane)) * 8;

  f32x4 accq[4][4], acck[4][4];
#pragma unroll
  for (int mb = 0; mb < 4; ++mb)
#pragma unroll
    for (int nb = 0; nb < 4; ++nb) {
      accq[mb][nb] = (f32x4){0.f, 0.f, 0.f, 0.f};
      acck[mb][nb] = (f32x4){0.f, 0.f, 0.f, 0.f};
    }

#define CONV_A(F0, F1, F2, F3, AH_, AL_)                                  \
  do {                                                                    \
    float av0[8] = {F0.x, F0.y, F0.z, F0.w, F1.x, F1.y, F1.z, F1.w};      \
    float av1[8] = {F2.x, F2.y, F2.z, F2.w, F3.x, F3.y, F3.z, F3.w};      \
    half8 h0, h1, l0, l1;                                                 \
    _Pragma("unroll") for (int j = 0; j < 8; ++j) {                       \
      _Float16 a = (_Float16)av0[j];                                      \
      h0[j] = a;                                                          \
      l0[j] = (_Float16)(av0[j] - (float)a);                              \
      _Float16 b = (_Float16)av1[j];                                      \
      h1[j] = b;                                                          \
      l1[j] = (_Float16)(av1[j] - (float)b);                              \
    }                                                                     \
    *(half8*)((AH_) + tid * 8) = h0;                                      \
    *(half8*)((AH_) + (tid + 256) * 8) = h1;                              \
    *(half8*)((AL_) + tid * 8) = l0;                                      \
    *(half8*)((AL_) + (tid + 256) * 8) = l1;                              \
  } while (0)

#define COMPUTE(AH_, AL_, KTV)                                            \
  do {                                                                    \
    const _Float16* bqp = bqb + (long)(KTV) * 16384;                      \
    const _Float16* bkp = bkb + (long)(KTV) * 16384;                      \
    half8 bq[4], bk[4], ah[4], al[4];                                     \
    _Pragma("unroll") for (int nb = 0; nb < 4; ++nb) {                    \
      bq[nb] = *(const half8*)(bqp + nb * 512);                           \
      bk[nb] = *(const half8*)(bkp + nb * 512);                           \
    }                                                                     \
    _Pragma("unroll") for (int mb = 0; mb < 4; ++mb) {                    \
      const int cm = wrow * 4 + mb;                                       \
      ah[mb] = *(const half8*)((AH_) + (cm * 64 + lane) * 8);             \
      al[mb] = *(const half8*)((AL_) + (cm * 64 + lane) * 8);             \
    }                                                                     \
    __builtin_amdgcn_s_setprio(1);                                        \
    _Pragma("unroll") for (int nb = 0; nb < 4; ++nb)                      \
        _Pragma("unroll") for (int mb = 0; mb < 4; ++mb) {                \
      accq[mb][nb] = __builtin_amdgcn_mfma_f32_16x16x32_f16(              \
          ah[mb], bq[nb], accq[mb][nb], 0, 0, 0);                         \
      acck[mb][nb] = __builtin_amdgcn_mfma_f32_16x16x32_f16(              \
          ah[mb], bk[nb], acck[mb][nb], 0, 0, 0);                         \
      accq[mb][nb] = __builtin_amdgcn_mfma_f32_16x16x32_f16(              \
          al[mb], bq[nb], accq[mb][nb], 0, 0, 0);                         \
      acck[mb][nb] = __builtin_amdgcn_mfma_f32_16x16x32_f16(              \
          al[mb], bk[nb], acck[mb][nb], 0, 0, 0);                         \
    }                                                                     \
    __builtin_amdgcn_s_setprio(0);                                        \
  } while (0)

  // ---- prologue: A(0) into buf0, prefetch A(1) regs ----
  float4 pa0 = *(const float4*)(ap);
  float4 pa1 = *(const float4*)(ap + 4);
  float4 pa2 = *(const float4*)(ap + 64 * 512);
  float4 pa3 = *(const float4*)(ap + 64 * 512 + 4);
  CONV_A(pa0, pa1, pa2, pa3, AH0, AL0);
  float4 pb0 = *(const float4*)(ap + 32);
  float4 pb1 = *(const float4*)(ap + 32 + 4);
  float4 pb2 = *(const float4*)(ap + 32 + 64 * 512);
  float4 pb3 = *(const float4*)(ap + 32 + 64 * 512 + 4);
  BARRIER();

  for (int i = 0; i < 8; ++i) {
    const int kt = 2 * i;
    // ---- even step: compute buf0(kt); stage A(kt+1) -> buf1 ----
    CONV_A(pb0, pb1, pb2, pb3, AH1, AL1);
    if (i < 7) {
      const float* xp = ap + (kt + 2) * 32;
      pa0 = *(const float4*)(xp);
      pa1 = *(const float4*)(xp + 4);
      pa2 = *(const float4*)(xp + 64 * 512);
      pa3 = *(const float4*)(xp + 64 * 512 + 4);
    }
    COMPUTE(AH0, AL0, kt);
    BARRIER();
    // ---- odd step: compute buf1(kt+1); stage A(kt+2) -> buf0 ----
    if (i < 7) {
      CONV_A(pa0, pa1, pa2, pa3, AH0, AL0);
      const float* xp2 = ap + (kt + 3) * 32;
      pb0 = *(const float4*)(xp2);
      pb1 = *(const float4*)(xp2 + 4);
      pb2 = *(const float4*)(xp2 + 64 * 512);
      pb3 = *(const float4*)(xp2 + 64 * 512 + 4);
    }
    COMPUTE(AH1, AL1, kt + 1);
    BARRIER();
  }

  // ---------------- epilogue ----------------
  // k-acc -> LDS (f16), row-major stride 136 halfs (=272 B) so the 4 g-rows
  // of a read/write group land on different banks. 128*136*2 B = 34 KB.
  _Float16* KX = smem;
  const int col0 = wcol * 64 + n;
  const int rbase = wrow * 64;
#pragma unroll
  for (int mb = 0; mb < 4; ++mb)
#pragma unroll
    for (int reg = 0; reg < 4; ++reg) {
      const int rl = rbase + mb * 16 + g * 4 + reg;
#pragma unroll
      for (int nb = 0; nb < 4; ++nb)
        KX[rl * 136 + col0 + nb * 16] = (_Float16)acck[mb][nb][reg];
    }
  __syncthreads();

  // block-boundary edges: k local row 127 and q local row 0 (f32, 128 cols
  // per (rb,cb) block -> full 512 cols per rb across cb).
  if (wrow == 1 && g == 3) {
#pragma unroll
    for (int nb = 0; nb < 4; ++nb)
      kedge[rb * 512 + cb * 128 + col0 + nb * 16] = acck[3][nb][3];
  }
  if (wrow == 0 && g == 0) {
#pragma unroll
    for (int nb = 0; nb < 4; ++nb)
      qedge[rb * 512 + cb * 128 + col0 + nb * 16] = accq[0][nb][0];
  }

  // per-row partials: ssq, ssk, dot = q[r] . k[r-1] (k from LDS, f16).
  // Local row 0's dot comes from edgedot.
#pragma unroll
  for (int mb = 0; mb < 4; ++mb) {
#pragma unroll
    for (int reg = 0; reg < 4; ++reg) {
      const int rl = rbase + mb * 16 + g * 4 + reg;
      const long row = r0 + rl;
      float sq = 0.f, sk = 0.f, dt = 0.f;
#pragma unroll
      for (int nb = 0; nb < 4; ++nb) {
        float qv = accq[mb][nb][reg];
        float kv = acck[mb][nb][reg];
        sq = fmaf(qv, qv, sq);
        sk = fmaf(kv, kv, sk);
        if (rl > 0) {
          float kp = (float)KX[(rl - 1) * 136 + col0 + nb * 16];
          dt = fmaf(qv, kp, dt);
        }
      }
#pragma unroll
      for (int m = 1; m < 16; m <<= 1) {
        sq += __shfl_xor(sq, m, 64);
        sk += __shfl_xor(sk, m, 64);
        dt += __shfl_xor(dt, m, 64);
      }
      if (n == 0) {
        atomicAdd(&ssqOut[row], sq);
        atomicAdd(&sskOut[row], sk);
        if (rl > 0) atomicAdd(&dotOut[row], dt);
      }
    }
  }
#undef CONV_A
#undef COMPUTE
}

// ---------------------------------------------------------------------------
// Boundary rows (r multiple of 128, r's l != 0): dot = qedge[rb] . kedge[rb-1]
// over all 512 cols. Sole writer of dotOut for these rows.
// ---------------------------------------------------------------------------
__global__ __launch_bounds__(64) void edgedot(
    const float* __restrict__ qedge, const float* __restrict__ kedge,
    float* __restrict__ dotOut) {
  const int rb = blockIdx.x;  // 0..511
  if (rb == 0) return;
  const long row = (long)rb * 128;
  if ((row & (LL - 1)) == 0) return;  // l == 0: p forced to 1, dot unused
  const int lane = threadIdx.x;
  float dt = 0.f;
#pragma unroll
  for (int c = lane; c < 512; c += 64)
    dt = fmaf(qedge[rb * 512 + c], kedge[(rb - 1) * 512 + c], dt);
#pragma unroll
  for (int m = 1; m < 64; m <<= 1) dt += __shfl_xor(dt, m, 64);
  if (lane == 0) dotOut[row] = dt;
}

// ---------------------------------------------------------------------------
// Combine: cos from partials -> p, b_hard, fixlist.
// ---------------------------------------------------------------------------
__global__ __launch_bounds__(256) void combine(
    const float* __restrict__ ssq, const float* __restrict__ ssk,
    const float* __restrict__ dotb, float* __restrict__ dout,
    int* __restrict__ fixlist, int* __restrict__ fixcnt) {
  const int r = blockIdx.x * 256 + threadIdx.x;
  const int l = r & (LL - 1);
  float p;
  float cosv = 0.0f;
  if (l != 0) {
    float nq = fmaxf(sqrtf(ssq[r]), 1e-12f);
    float nk = fmaxf(sqrtf(ssk[r - 1]), 1e-12f);
    cosv = dotb[r] / (nq * nk);
    p = fminf(fmaxf(0.5f * (1.0f - cosv), 0.0f), 1.0f);
  } else {
    p = 1.0f;
  }
  dout[OUT_P + r] = p;
  dout[OUT_BHARD + r] = (p >= 0.5f) ? 1.0f : 0.0f;
  if (l != 0 && fabsf(cosv) < FIX_TAU) {
    int idx = atomicAdd(fixcnt, 1);
    if (idx < FIX_CAP) fixlist[idx] = r;
  }
}

// ---------------------------------------------------------------------------
// f64 recompute of borderline rows (expected ~120 rows at TAU=1e-4).
// ---------------------------------------------------------------------------
__global__ __launch_bounds__(256) void fixup(
    const float* __restrict__ x, const float* __restrict__ Wq,
    const float* __restrict__ Wk, float* __restrict__ dout,
    const int* __restrict__ fixlist, const int* __restrict__ fixcnt) {
  __shared__ float xr[512], xp[512];
  __shared__ double red[3][256];
  const int t = threadIdx.x;
  int nfix = *fixcnt;
  if (nfix > FIX_CAP) nfix = FIX_CAP;

  for (int idx = blockIdx.x; idx < nfix; idx += gridDim.x) {
    const int r = fixlist[idx];
    for (int d = t; d < 512; d += 256) {
      xr[d] = x[(long)r * 512 + d];
      xp[d] = x[(long)(r - 1) * 512 + d];
    }
    __syncthreads();
    double ssq = 0.0, ssk = 0.0, dot = 0.0;
    for (int e = t; e < 512; e += 256) {
      const float* wq = Wq + (long)e * 512;
      const float* wk = Wk + (long)e * 512;
      double q = 0.0, k = 0.0;
      for (int d = 0; d < 512; ++d) {
        q = fma((double)xr[d], (double)wq[d], q);
        k = fma((double)xp[d], (double)wk[d], k);
      }
      ssq += q * q;
      ssk += k * k;
      dot += q * k;
    }
    red[0][t] = ssq;
    red[1][t] = ssk;
    red[2][t] = dot;
    __syncthreads();
    for (int s = 128; s > 0; s >>= 1) {
      if (t < s) {
        red[0][t] += red[0][t + s];
        red[1][t] += red[1][t + s];
        red[2][t] += red[2][t + s];
      }
      __syncthreads();
    }
    if (t == 0) {
      double nq = sqrt(red[0][0]);
      double nk = sqrt(red[1][0]);
      if (nq < 1e-12) nq = 1e-12;
      if (nk < 1e-12) nk = 1e-12;
      float c = (float)(red[2][0] / (nq * nk));
      float p = fminf(fmaxf(0.5f * (1.0f - c), 0.0f), 1.0f);
      dout[OUT_P + r] = p;
      dout[OUT_BHARD + r] = (p >= 0.5f) ? 1.0f : 0.0f;
    }
    __syncthreads();
  }
}

// ---------------------------------------------------------------------------
// Per-batch scan (shfl-based), mask, p_compressed, sel, counts.
// ---------------------------------------------------------------------------
__global__ __launch_bounds__(256) void scanb(
    float* __restrict__ dout, int* __restrict__ sel,
    int* __restrict__ counts, float* __restrict__ sump) {
  __shared__ int wtot[4];
  __shared__ float wps[4];
  const int b = blockIdx.x;
  const int t = threadIdx.x;
  const int lane = t & 63, wv = t >> 6;
  const long base = (long)b * LL;

  int cnt = 0;
  float psum = 0.0f;
#pragma unroll 4
  for (int j = 0; j < 32; ++j) {
    int l = t * 32 + j;
    float bh = dout[OUT_BHARD + base + l];
    float pv = dout[OUT_P + base + l];
    cnt += (bh > 0.5f) ? 1 : 0;
    psum += pv;
  }
  int inc = cnt;
#pragma unroll
  for (int off = 1; off < 64; off <<= 1) {
    int u = __shfl_up(inc, off, 64);
    if (lane >= off) inc += u;
  }
  float ps = psum;
#pragma unroll
  for (int off = 1; off < 64; off <<= 1) ps += __shfl_xor(ps, off, 64);
  if (lane == 63) wtot[wv] = inc;
  if (lane == 0) wps[wv] = ps;
  __syncthreads();
  int wbase = 0, total = 0;
#pragma unroll
  for (int i = 0; i < 4; ++i) {
    int c = wtot[i];
    if (i < wv) wbase += c;
    total += c;
  }
  if (t == 0) {
    counts[b] = total;
    sump[b] = wps[0] + wps[1] + wps[2] + wps[3];
  }
  for (int j = 0; j < 32; ++j) {
    int l = t * 32 + j;
    dout[OUT_MASK + base + l] = (l < total) ? 1.0f : 0.0f;
    dout[OUT_PCOMP + base + l] = 0.0f;
  }
  __syncthreads();
  int pos = wbase + inc - cnt;  // exclusive prefix
  for (int j = 0; j < 32; ++j) {
    int l = t * 32 + j;
    float bh = dout[OUT_BHARD + base + l];
    if (bh > 0.5f) {
      dout[OUT_PCOMP + base + pos] = dout[OUT_P + base + l];
      sel[base + pos] = l;
      ++pos;
    }
  }
}

// ---------------------------------------------------------------------------
__global__ void lossk(float* __restrict__ dout, const int* __restrict__ counts,
                      const float* __restrict__ sump) {
  if (threadIdx.x == 0 && blockIdx.x == 0) {
    float fc = 0.0f, gs = 0.0f;
    for (int b = 0; b < BB; ++b) {
      fc += (float)counts[b];
      gs += sump[b];
    }
    float F = fc / (float)NROWS;
    float G = gs / (float)NROWS;
    dout[OUT_LOSS] = 1.2f * (5.0f * F * G + (1.0f - F) * (1.0f - G));
  }
}

// ---------------------------------------------------------------------------
__global__ __launch_bounds__(128) void emit(
    const float* __restrict__ x, float* __restrict__ dout,
    const int* __restrict__ sel, const int* __restrict__ counts) {
  const long bid = blockIdx.x;
  const int b = (int)(bid >> 13);
  const int j = (int)(bid & (LL - 1));
  const int cnt = counts[b];
  float4 v = make_float4(0.0f, 0.0f, 0.0f, 0.0f);
  if (j < cnt) {
    const int l = sel[((long)b << 13) + j];
    v = *(const float4*)(x + (((long)b << 13) + l) * 512 + threadIdx.x * 4);
  }
  *(float4*)(dout + OUT_COMP + (((long)b << 13) + j) * 512 + threadIdx.x * 4) = v;
}

// ---------------------------------------------------------------------------
extern "C" void kernel_launch(void* const* d_in, const int* in_sizes, int n_in,
                              void* d_out, int out_size, void* d_ws,
                              size_t ws_size, hipStream_t stream) {
  const float* x = (const float*)d_in[0];
  const float* Wq = (const float*)d_in[1];
  const float* Wk = (const float*)d_in[2];
  float* out = (float*)d_out;
  char* ws = (char*)d_ws;

  int* fixlist = (int*)(ws + WS_FIXLIST);
  int* fixcnt = (int*)(ws + WS_FIXCNT);
  int* counts = (int*)(ws + WS_COUNTS);
  float* sump = (float*)(ws + WS_SUMP);
  int* sel = (int*)(ws + WS_SEL);
  float* ssk = (float*)(ws + WS_SSK);
  float* ssq = (float*)(ws + WS_SSQ);
  float* dotb = (float*)(ws + WS_DOT);
  _Float16* wqh = (_Float16*)(ws + WS_WQH);
  _Float16* wkh = (_Float16*)(ws + WS_WKH);

  // edge buffers (512x512 f32 each = 1 MB) staged in d_out's compressed
  // region; emit overwrites it at the end.
  float* kedge = (float*)(out + OUT_COMP);
  float* qedge = (float*)(out + OUT_COMP + 262144);

  wsplit<<<256, 256, 0, stream>>>(Wq, Wk, wqh, wkh, ssk, ssq, dotb, fixcnt);
  gemm_fused<<<2048, 256, 0, stream>>>(x, wqh, wkh, ssq, ssk, dotb, qedge, kedge);
  edgedot<<<512, 64, 0, stream>>>(qedge, kedge, dotb);
  combine<<<NROWS / 256, 256, 0, stream>>>(ssq, ssk, dotb, out, fixlist, fixcnt);
  fixup<<<512, 256, 0, stream>>>(x, Wq, Wk, out, fixlist, fixcnt);
  scanb<<<BB, 256, 0, stream>>>(out, sel, counts, sump);
  lossk<<<1, 64, 0, stream>>>(out, counts, sump);
  emit<<<NROWS, 128, 0, stream>>>(x, out, sel, counts);
}

// Round 4
// 468.738 us; speedup vs baseline: 1.1378x; 1.0394x over previous
//
#include <hip/hip_runtime.h>
#include <hip/hip_bf16.h>
#include <math.h>

// Problem constants
#define BB 8
#define LL 8192
#define DD 512
#define NROWS (BB * LL)  // 65536

// d_out layout (floats)
#define OUT_COMP   0
#define OUT_MASK   33554432
#define OUT_BHARD  33619968
#define OUT_P      33685504
#define OUT_PCOMP  33751040
#define OUT_LOSS   33816576

// ws layout (bytes)
#define WS_FIXLIST 0         // 65536*4
#define WS_FIXCNT  262144    // 4
#define WS_COUNTS  262148    // 32
#define WS_SUMP    262180    // 32
#define WS_SEL     262212    // 65536*4 -> 524356
#define WS_SSK     524416    // 65536*4
#define WS_SSQ     786560    // 65536*4
#define WS_DOT     1048704   // 65536*4
#define WS_WQH     1310848   // 512 KB each
#define WS_WKH     1835136   // end ~2.4 MB

#define FIX_CAP 65536
// 2-pairing cos error rms ~2e-6 (dropped al*bl term is ~5e-8); 1e-4 = 50 sigma
#define FIX_TAU 1e-4f

typedef __attribute__((ext_vector_type(8))) _Float16 half8;
typedef __attribute__((ext_vector_type(4))) float f32x4;

// async global->LDS, 16 B per lane; lds base wave-uniform, data lands at
// lds + lane*16 (m104/m108) -- layouts below are lane-sequential.
static __device__ __forceinline__ void ld_g2l16(const void* g, void* l) {
  __builtin_amdgcn_global_load_lds(
      (const __attribute__((address_space(1))) void*)g,
      (__attribute__((address_space(3))) void*)l, 16, 0, 0);
}

// ---------------------------------------------------------------------------
// Pass 0: split Wq,Wk into f16 hi (2-pairing GEMM: A hi/lo x B hi),
// fragment-chunk order: chunk c = (kt*32 + ct)*64 + kblk*16 + n holds
// W[e = ct*16+n][d = kt*32 + kblk*8 .. +8]. Also zero-inits accumulators.
// ---------------------------------------------------------------------------
__global__ __launch_bounds__(256) void wsplit(
    const float* __restrict__ Wq, const float* __restrict__ Wk,
    _Float16* __restrict__ wqh, _Float16* __restrict__ wkh,
    float* __restrict__ ssk, float* __restrict__ ssq,
    float* __restrict__ dotb, int* __restrict__ fixcnt) {
  const int t = blockIdx.x * 256 + threadIdx.x;  // 0..65535
  if (t == 0) *fixcnt = 0;
  ssk[t] = 0.0f;
  ssq[t] = 0.0f;
  dotb[t] = 0.0f;

  const int m = t >> 15;         // 0 = Wq, 1 = Wk
  const int c = t & 32767;       // chunk id
  const int kt = c >> 11;
  const int ct = (c >> 6) & 31;
  const int l = c & 63;
  const int n = l & 15;
  const int kblk = l >> 4;
  const int e = ct * 16 + n;
  const int d0 = kt * 32 + kblk * 8;
  const float* src = (m ? Wk : Wq) + (long)e * 512 + d0;
  _Float16* dh = (m ? wkh : wqh) + (long)c * 8;
  float4 v0 = *(const float4*)src;
  float4 v1 = *(const float4*)(src + 4);
  float av[8] = {v0.x, v0.y, v0.z, v0.w, v1.x, v1.y, v1.z, v1.w};
  half8 hi;
#pragma unroll
  for (int j = 0; j < 8; ++j) hi[j] = (_Float16)av[j];
  *(half8*)dh = hi;
}

// ---------------------------------------------------------------------------
// FUSED GEMM: q = x*Wq^T and k = x*Wk^T in one pass. 128x128 tile, BK=32,
// 4 waves 2x2. 2-pairing f16 split (ah*bh + al*bh).
// Pipeline per K-step (counted-vmcnt, T3/T4):
//   1. issue B g2l(kt+1) -> Bbuf[nxt]      [4 vmem ops, OLDEST]
//   2. issue A f32 loads(kt+2) -> regs     [4 vmem ops, younger]
//   3. CONV_A(regs kt+1 -> Abuf[nxt])      [ds_writes]
//   4. ds_read frags(cur) + 64 MFMA
//   5. s_waitcnt vmcnt(4)  -- drains MY B g2l only; A HBM loads stay in
//      flight across the barrier. lgkmcnt(0) publishes ds_writes. s_barrier.
// sched_barrier(0) fences pin issue order so the vmcnt count is exact.
// XCD-swizzled blockIdx so the 4 cb-siblings of an rb share L2 A-panels.
// ---------------------------------------------------------------------------
__global__ __launch_bounds__(256, 2) void gemm_fused(
    const float* __restrict__ x,
    const _Float16* __restrict__ wqh, const _Float16* __restrict__ wkh,
    float* __restrict__ ssqOut, float* __restrict__ sskOut,
    float* __restrict__ dotOut,
    float* __restrict__ qedge, float* __restrict__ kedge) {
  __shared__ _Float16 smem[32768];  // 64 KB: A dbuf (32 KB) + B dbuf (32 KB)
  _Float16* AH0 = smem;             // chunks: (mbs*64 + kblk*16 + ms)
  _Float16* AL0 = smem + 4096;
  _Float16* AH1 = smem + 8192;
  _Float16* AL1 = smem + 12288;
  _Float16* BQ0 = smem + 16384;     // chunks: (ctl*64 + kblk*16 + n)
  _Float16* BK0 = smem + 20480;
  _Float16* BQ1 = smem + 24576;
  _Float16* BK1 = smem + 28672;

  const int tid = threadIdx.x;
  const int lane = tid & 63;
  const int w = tid >> 6;
  const int wrow = w & 1, wcol = w >> 1;
  const int g = lane >> 4, n = lane & 15;
  const int bx0 = blockIdx.x;
  const int bx = ((bx0 & 7) << 8) | (bx0 >> 3);  // XCD-contiguous (2048 = 8*256)
  const int rb = bx >> 2, cb = bx & 3;
  const long r0 = (long)rb * 128;

  // A staging: tid = (mbs<<6)|(kblk<<4)|ms -> chunk c1=tid (row arow),
  // chunk c2=tid+256 (row arow+64). 8 consecutive floats at col akb*8.
  const int arow = ((tid >> 6) << 4) | (tid & 15);
  const int akb = (tid >> 4) & 3;
  const float* ap = x + (r0 + arow) * 512 + akb * 8;

  f32x4 accq[4][4], acck[4][4];
#pragma unroll
  for (int mb = 0; mb < 4; ++mb)
#pragma unroll
    for (int nb = 0; nb < 4; ++nb) {
      accq[mb][nb] = (f32x4){0.f, 0.f, 0.f, 0.f};
      acck[mb][nb] = (f32x4){0.f, 0.f, 0.f, 0.f};
    }

  // stage B tile ktv into (BQ_, BK_): 4 g2l ops per wave (wave w covers
  // 1024 halfs of each buffer).
#define STAGE_B(ktv, BQ_, BK_)                                              \
  do {                                                                      \
    const long bb = ((long)((ktv)*32 + cb * 8) << 9) + w * 1024 + lane * 8; \
    ld_g2l16(wqh + bb, (BQ_) + w * 1024);                                   \
    ld_g2l16(wqh + bb + 512, (BQ_) + w * 1024 + 512);                       \
    ld_g2l16(wkh + bb, (BK_) + w * 1024);                                   \
    ld_g2l16(wkh + bb + 512, (BK_) + w * 1024 + 512);                       \
  } while (0)

#define CONV_A(F0, F1, F2, F3, AH_, AL_)                                  \
  do {                                                                    \
    float av0[8] = {F0.x, F0.y, F0.z, F0.w, F1.x, F1.y, F1.z, F1.w};      \
    float av1[8] = {F2.x, F2.y, F2.z, F2.w, F3.x, F3.y, F3.z, F3.w};      \
    half8 h0, h1, l0, l1;                                                 \
    _Pragma("unroll") for (int j = 0; j < 8; ++j) {                       \
      _Float16 a = (_Float16)av0[j];                                      \
      h0[j] = a;                                                          \
      l0[j] = (_Float16)(av0[j] - (float)a);                              \
      _Float16 b = (_Float16)av1[j];                                      \
      h1[j] = b;                                                          \
      l1[j] = (_Float16)(av1[j] - (float)b);                              \
    }                                                                     \
    *(half8*)((AH_) + tid * 8) = h0;                                      \
    *(half8*)((AH_) + (tid + 256) * 8) = h1;                              \
    *(half8*)((AL_) + tid * 8) = l0;                                      \
    *(half8*)((AL_) + (tid + 256) * 8) = l1;                              \
  } while (0)

#define COMPUTE(AH_, AL_, BQ_, BK_)                                       \
  do {                                                                    \
    half8 ah[4], al[4], bq[4], bk[4];                                     \
    _Pragma("unroll") for (int nb = 0; nb < 4; ++nb) {                    \
      bq[nb] = *(const half8*)((BQ_) + ((wcol * 4 + nb) * 64 + lane) * 8);\
      bk[nb] = *(const half8*)((BK_) + ((wcol * 4 + nb) * 64 + lane) * 8);\
    }                                                                     \
    _Pragma("unroll") for (int mb = 0; mb < 4; ++mb) {                    \
      const int cm = wrow * 4 + mb;                                       \
      ah[mb] = *(const half8*)((AH_) + (cm * 64 + lane) * 8);             \
      al[mb] = *(const half8*)((AL_) + (cm * 64 + lane) * 8);             \
    }                                                                     \
    __builtin_amdgcn_s_setprio(1);                                        \
    _Pragma("unroll") for (int nb = 0; nb < 4; ++nb)                      \
        _Pragma("unroll") for (int mb = 0; mb < 4; ++mb) {                \
      accq[mb][nb] = __builtin_amdgcn_mfma_f32_16x16x32_f16(              \
          ah[mb], bq[nb], accq[mb][nb], 0, 0, 0);                         \
      acck[mb][nb] = __builtin_amdgcn_mfma_f32_16x16x32_f16(              \
          ah[mb], bk[nb], acck[mb][nb], 0, 0, 0);                         \
      accq[mb][nb] = __builtin_amdgcn_mfma_f32_16x16x32_f16(              \
          al[mb], bq[nb], accq[mb][nb], 0, 0, 0);                         \
      acck[mb][nb] = __builtin_amdgcn_mfma_f32_16x16x32_f16(              \
          al[mb], bk[nb], acck[mb][nb], 0, 0, 0);                        \
    }                                                                     \
    __builtin_amdgcn_s_setprio(0);                                        \
  } while (0)

  // counted barrier: drain MY B-g2l (4 oldest vmem), leave the 4 A-HBM
  // loads in flight; publish ds_writes; sync.
#define BARRIER_CNT()                                       \
  do {                                                      \
    asm volatile("s_waitcnt vmcnt(4)" ::: "memory");        \
    asm volatile("s_waitcnt lgkmcnt(0)" ::: "memory");      \
    __builtin_amdgcn_sched_barrier(0);                      \
    __builtin_amdgcn_s_barrier();                           \
  } while (0)

#define FENCE() __builtin_amdgcn_sched_barrier(0)

  // ---- prologue ----
  STAGE_B(0, BQ0, BK0);                     // [4] oldest
  FENCE();
  float4 pa0 = *(const float4*)(ap);        // A(0) f32
  float4 pa1 = *(const float4*)(ap + 4);
  float4 pa2 = *(const float4*)(ap + 64 * 512);
  float4 pa3 = *(const float4*)(ap + 64 * 512 + 4);
  FENCE();
  CONV_A(pa0, pa1, pa2, pa3, AH0, AL0);     // auto-waits pa*
  float4 pb0 = *(const float4*)(ap + 32);   // A(1) f32, younger than B(0)
  float4 pb1 = *(const float4*)(ap + 32 + 4);
  float4 pb2 = *(const float4*)(ap + 32 + 64 * 512);
  float4 pb3 = *(const float4*)(ap + 32 + 64 * 512 + 4);
  FENCE();
  BARRIER_CNT();  // B(0) done; A(1) flying

  for (int i = 0; i < 8; ++i) {
    const int kt = 2 * i;
    // ---- even step kt: compute buf0; stage B(kt+1)->buf1, conv A(kt+1),
    //      load A(kt+2) ----
    STAGE_B(kt + 1, BQ1, BK1);
    FENCE();
    {
      const int ktn = (kt + 2 < 16) ? (kt + 2) : 15;  // clamped (dummy ok)
      const float* xp = ap + ktn * 32;
      pa0 = *(const float4*)(xp);
      pa1 = *(const float4*)(xp + 4);
      pa2 = *(const float4*)(xp + 64 * 512);
      pa3 = *(const float4*)(xp + 64 * 512 + 4);
    }
    FENCE();
    CONV_A(pb0, pb1, pb2, pb3, AH1, AL1);
    COMPUTE(AH0, AL0, BQ0, BK0);
    BARRIER_CNT();
    // ---- odd step kt+1: compute buf1; stage B(kt+2)->buf0, conv A(kt+2),
    //      load A(kt+3) ----
    {
      const int ktn = (kt + 2 < 16) ? (kt + 2) : 15;  // dummy restage on last
      STAGE_B(ktn, BQ0, BK0);
    }
    FENCE();
    {
      const int ktn = (kt + 3 < 16) ? (kt + 3) : 15;
      const float* xp2 = ap + ktn * 32;
      pb0 = *(const float4*)(xp2);
      pb1 = *(const float4*)(xp2 + 4);
      pb2 = *(const float4*)(xp2 + 64 * 512);
      pb3 = *(const float4*)(xp2 + 64 * 512 + 4);
    }
    FENCE();
    CONV_A(pa0, pa1, pa2, pa3, AH0, AL0);
    COMPUTE(AH1, AL1, BQ1, BK1);
    BARRIER_CNT();
  }

  // drain all in-flight vmem (last dummy g2l targets B area, which overlaps
  // the epilogue KX buffer) before reusing smem.
  asm volatile("s_waitcnt vmcnt(0)" ::: "memory");
  __builtin_amdgcn_sched_barrier(0);
  __syncthreads();

  // ---------------- epilogue ----------------
  // k-acc -> LDS (f16), row-major stride 136 halfs (=272 B) so the 4 g-rows
  // of a read/write group land on different banks. 128*136*2 B = 34 KB.
  _Float16* KX = smem;
  const int col0 = wcol * 64 + n;
  const int rbase = wrow * 64;
#pragma unroll
  for (int mb = 0; mb < 4; ++mb)
#pragma unroll
    for (int reg = 0; reg < 4; ++reg) {
      const int rl = rbase + mb * 16 + g * 4 + reg;
#pragma unroll
      for (int nb = 0; nb < 4; ++nb)
        KX[rl * 136 + col0 + nb * 16] = (_Float16)acck[mb][nb][reg];
    }
  __syncthreads();

  // block-boundary edges: k local row 127 and q local row 0 (f32, 128 cols
  // per (rb,cb) block -> full 512 cols per rb across cb).
  if (wrow == 1 && g == 3) {
#pragma unroll
    for (int nb = 0; nb < 4; ++nb)
      kedge[rb * 512 + cb * 128 + col0 + nb * 16] = acck[3][nb][3];
  }
  if (wrow == 0 && g == 0) {
#pragma unroll
    for (int nb = 0; nb < 4; ++nb)
      qedge[rb * 512 + cb * 128 + col0 + nb * 16] = accq[0][nb][0];
  }

  // per-row partials: ssq, ssk, dot = q[r] . k[r-1] (k from LDS, f16).
  // Local row 0's dot comes from edgedot.
#pragma unroll
  for (int mb = 0; mb < 4; ++mb) {
#pragma unroll
    for (int reg = 0; reg < 4; ++reg) {
      const int rl = rbase + mb * 16 + g * 4 + reg;
      const long row = r0 + rl;
      float sq = 0.f, sk = 0.f, dt = 0.f;
#pragma unroll
      for (int nb = 0; nb < 4; ++nb) {
        float qv = accq[mb][nb][reg];
        float kv = acck[mb][nb][reg];
        sq = fmaf(qv, qv, sq);
        sk = fmaf(kv, kv, sk);
        if (rl > 0) {
          float kp = (float)KX[(rl - 1) * 136 + col0 + nb * 16];
          dt = fmaf(qv, kp, dt);
        }
      }
#pragma unroll
      for (int m = 1; m < 16; m <<= 1) {
        sq += __shfl_xor(sq, m, 64);
        sk += __shfl_xor(sk, m, 64);
        dt += __shfl_xor(dt, m, 64);
      }
      if (n == 0) {
        atomicAdd(&ssqOut[row], sq);
        atomicAdd(&sskOut[row], sk);
        if (rl > 0) atomicAdd(&dotOut[row], dt);
      }
    }
  }
#undef STAGE_B
#undef CONV_A
#undef COMPUTE
#undef BARRIER_CNT
#undef FENCE
}

// ---------------------------------------------------------------------------
// Boundary rows (r multiple of 128, r's l != 0): dot = qedge[rb] . kedge[rb-1]
// over all 512 cols. Sole writer of dotOut for these rows.
// ---------------------------------------------------------------------------
__global__ __launch_bounds__(64) void edgedot(
    const float* __restrict__ qedge, const float* __restrict__ kedge,
    float* __restrict__ dotOut) {
  const int rb = blockIdx.x;  // 0..511
  if (rb == 0) return;
  const long row = (long)rb * 128;
  if ((row & (LL - 1)) == 0) return;  // l == 0: p forced to 1, dot unused
  const int lane = threadIdx.x;
  float dt = 0.f;
#pragma unroll
  for (int c = lane; c < 512; c += 64)
    dt = fmaf(qedge[rb * 512 + c], kedge[(rb - 1) * 512 + c], dt);
#pragma unroll
  for (int m = 1; m < 64; m <<= 1) dt += __shfl_xor(dt, m, 64);
  if (lane == 0) dotOut[row] = dt;
}

// ---------------------------------------------------------------------------
// Combine: cos from partials -> p, b_hard, fixlist.
// ---------------------------------------------------------------------------
__global__ __launch_bounds__(256) void combine(
    const float* __restrict__ ssq, const float* __restrict__ ssk,
    const float* __restrict__ dotb, float* __restrict__ dout,
    int* __restrict__ fixlist, int* __restrict__ fixcnt) {
  const int r = blockIdx.x * 256 + threadIdx.x;
  const int l = r & (LL - 1);
  float p;
  float cosv = 0.0f;
  if (l != 0) {
    float nq = fmaxf(sqrtf(ssq[r]), 1e-12f);
    float nk = fmaxf(sqrtf(ssk[r - 1]), 1e-12f);
    cosv = dotb[r] / (nq * nk);
    p = fminf(fmaxf(0.5f * (1.0f - cosv), 0.0f), 1.0f);
  } else {
    p = 1.0f;
  }
  dout[OUT_P + r] = p;
  dout[OUT_BHARD + r] = (p >= 0.5f) ? 1.0f : 0.0f;
  if (l != 0 && fabsf(cosv) < FIX_TAU) {
    int idx = atomicAdd(fixcnt, 1);
    if (idx < FIX_CAP) fixlist[idx] = r;
  }
}

// ---------------------------------------------------------------------------
// f64 recompute of borderline rows (expected ~120 rows at TAU=1e-4).
// ---------------------------------------------------------------------------
__global__ __launch_bounds__(256) void fixup(
    const float* __restrict__ x, const float* __restrict__ Wq,
    const float* __restrict__ Wk, float* __restrict__ dout,
    const int* __restrict__ fixlist, const int* __restrict__ fixcnt) {
  __shared__ float xr[512], xp[512];
  __shared__ double red[3][256];
  const int t = threadIdx.x;
  int nfix = *fixcnt;
  if (nfix > FIX_CAP) nfix = FIX_CAP;

  for (int idx = blockIdx.x; idx < nfix; idx += gridDim.x) {
    const int r = fixlist[idx];
    for (int d = t; d < 512; d += 256) {
      xr[d] = x[(long)r * 512 + d];
      xp[d] = x[(long)(r - 1) * 512 + d];
    }
    __syncthreads();
    double ssq = 0.0, ssk = 0.0, dot = 0.0;
    for (int e = t; e < 512; e += 256) {
      const float* wq = Wq + (long)e * 512;
      const float* wk = Wk + (long)e * 512;
      double q = 0.0, k = 0.0;
      for (int d = 0; d < 512; ++d) {
        q = fma((double)xr[d], (double)wq[d], q);
        k = fma((double)xp[d], (double)wk[d], k);
      }
      ssq += q * q;
      ssk += k * k;
      dot += q * k;
    }
    red[0][t] = ssq;
    red[1][t] = ssk;
    red[2][t] = dot;
    __syncthreads();
    for (int s = 128; s > 0; s >>= 1) {
      if (t < s) {
        red[0][t] += red[0][t + s];
        red[1][t] += red[1][t + s];
        red[2][t] += red[2][t + s];
      }
      __syncthreads();
    }
    if (t == 0) {
      double nq = sqrt(red[0][0]);
      double nk = sqrt(red[1][0]);
      if (nq < 1e-12) nq = 1e-12;
      if (nk < 1e-12) nk = 1e-12;
      float c = (float)(red[2][0] / (nq * nk));
      float p = fminf(fmaxf(0.5f * (1.0f - c), 0.0f), 1.0f);
      dout[OUT_P + r] = p;
      dout[OUT_BHARD + r] = (p >= 0.5f) ? 1.0f : 0.0f;
    }
    __syncthreads();
  }
}

// ---------------------------------------------------------------------------
// Per-batch scan (shfl-based), mask, p_compressed, sel, counts.
// ---------------------------------------------------------------------------
__global__ __launch_bounds__(256) void scanb(
    float* __restrict__ dout, int* __restrict__ sel,
    int* __restrict__ counts, float* __restrict__ sump) {
  __shared__ int wtot[4];
  __shared__ float wps[4];
  const int b = blockIdx.x;
  const int t = threadIdx.x;
  const int lane = t & 63, wv = t >> 6;
  const long base = (long)b * LL;

  int cnt = 0;
  float psum = 0.0f;
#pragma unroll 4
  for (int j = 0; j < 32; ++j) {
    int l = t * 32 + j;
    float bh = dout[OUT_BHARD + base + l];
    float pv = dout[OUT_P + base + l];
    cnt += (bh > 0.5f) ? 1 : 0;
    psum += pv;
  }
  int inc = cnt;
#pragma unroll
  for (int off = 1; off < 64; off <<= 1) {
    int u = __shfl_up(inc, off, 64);
    if (lane >= off) inc += u;
  }
  float ps = psum;
#pragma unroll
  for (int off = 1; off < 64; off <<= 1) ps += __shfl_xor(ps, off, 64);
  if (lane == 63) wtot[wv] = inc;
  if (lane == 0) wps[wv] = ps;
  __syncthreads();
  int wbase = 0, total = 0;
#pragma unroll
  for (int i = 0; i < 4; ++i) {
    int c = wtot[i];
    if (i < wv) wbase += c;
    total += c;
  }
  if (t == 0) {
    counts[b] = total;
    sump[b] = wps[0] + wps[1] + wps[2] + wps[3];
  }
  for (int j = 0; j < 32; ++j) {
    int l = t * 32 + j;
    dout[OUT_MASK + base + l] = (l < total) ? 1.0f : 0.0f;
    dout[OUT_PCOMP + base + l] = 0.0f;
  }
  __syncthreads();
  int pos = wbase + inc - cnt;  // exclusive prefix
  for (int j = 0; j < 32; ++j) {
    int l = t * 32 + j;
    float bh = dout[OUT_BHARD + base + l];
    if (bh > 0.5f) {
      dout[OUT_PCOMP + base + pos] = dout[OUT_P + base + l];
      sel[base + pos] = l;
      ++pos;
    }
  }
}

// ---------------------------------------------------------------------------
__global__ void lossk(float* __restrict__ dout, const int* __restrict__ counts,
                      const float* __restrict__ sump) {
  if (threadIdx.x == 0 && blockIdx.x == 0) {
    float fc = 0.0f, gs = 0.0f;
    for (int b = 0; b < BB; ++b) {
      fc += (float)counts[b];
      gs += sump[b];
    }
    float F = fc / (float)NROWS;
    float G = gs / (float)NROWS;
    dout[OUT_LOSS] = 1.2f * (5.0f * F * G + (1.0f - F) * (1.0f - G));
  }
}

// ---------------------------------------------------------------------------
__global__ __launch_bounds__(128) void emit(
    const float* __restrict__ x, float* __restrict__ dout,
    const int* __restrict__ sel, const int* __restrict__ counts) {
  const long bid = blockIdx.x;
  const int b = (int)(bid >> 13);
  const int j = (int)(bid & (LL - 1));
  const int cnt = counts[b];
  float4 v = make_float4(0.0f, 0.0f, 0.0f, 0.0f);
  if (j < cnt) {
    const int l = sel[((long)b << 13) + j];
    v = *(const float4*)(x + (((long)b << 13) + l) * 512 + threadIdx.x * 4);
  }
  *(float4*)(dout + OUT_COMP + (((long)b << 13) + j) * 512 + threadIdx.x * 4) = v;
}

// ---------------------------------------------------------------------------
extern "C" void kernel_launch(void* const* d_in, const int* in_sizes, int n_in,
                              void* d_out, int out_size, void* d_ws,
                              size_t ws_size, hipStream_t stream) {
  const float* x = (const float*)d_in[0];
  const float* Wq = (const float*)d_in[1];
  const float* Wk = (const float*)d_in[2];
  float* out = (float*)d_out;
  char* ws = (char*)d_ws;

  int* fixlist = (int*)(ws + WS_FIXLIST);
  int* fixcnt = (int*)(ws + WS_FIXCNT);
  int* counts = (int*)(ws + WS_COUNTS);
  float* sump = (float*)(ws + WS_SUMP);
  int* sel = (int*)(ws + WS_SEL);
  float* ssk = (float*)(ws + WS_SSK);
  float* ssq = (float*)(ws + WS_SSQ);
  float* dotb = (float*)(ws + WS_DOT);
  _Float16* wqh = (_Float16*)(ws + WS_WQH);
  _Float16* wkh = (_Float16*)(ws + WS_WKH);

  // edge buffers (512x512 f32 each = 1 MB) staged in d_out's compressed
  // region; emit overwrites it at the end.
  float* kedge = (float*)(out + OUT_COMP);
  float* qedge = (float*)(out + OUT_COMP + 262144);

  wsplit<<<256, 256, 0, stream>>>(Wq, Wk, wqh, wkh, ssk, ssq, dotb, fixcnt);
  gemm_fused<<<2048, 256, 0, stream>>>(x, wqh, wkh, ssq, ssk, dotb, qedge, kedge);
  edgedot<<<512, 64, 0, stream>>>(qedge, kedge, dotb);
  combine<<<NROWS / 256, 256, 0, stream>>>(ssq, ssk, dotb, out, fixlist, fixcnt);
  fixup<<<512, 256, 0, stream>>>(x, Wq, Wk, out, fixlist, fixcnt);
  scanb<<<BB, 256, 0, stream>>>(out, sel, counts, sump);
  lossk<<<1, 64, 0, stream>>>(out, counts, sump);
  emit<<<NROWS, 128, 0, stream>>>(x, out, sel, counts);
}

// Round 5
// 457.203 us; speedup vs baseline: 1.1665x; 1.0252x over previous
//
#include <hip/hip_runtime.h>
#include <hip/hip_bf16.h>
#include <math.h>

// Problem constants
#define BB 8
#define LL 8192
#define DD 512
#define NROWS (BB * LL)  // 65536

// d_out layout (floats)
#define OUT_COMP   0
#define OUT_MASK   33554432
#define OUT_BHARD  33619968
#define OUT_P      33685504
#define OUT_PCOMP  33751040
#define OUT_LOSS   33816576

// ws layout (bytes)
#define WS_FIXLIST 0         // 65536*4
#define WS_FIXCNT  262144    // 4
#define WS_COUNTS  262148    // 32
#define WS_SUMP    262180    // 32
#define WS_SEL     262212    // 65536*4 -> 524356
#define WS_SSK     524416    // 65536*4
#define WS_SSQ     786560    // 65536*4
#define WS_DOT     1048704   // 65536*4
#define WS_WQH     1310848   // 512 KB each
#define WS_WKH     1835136   // end ~2.4 MB

#define FIX_CAP 65536
// 2-pairing cos error rms ~2e-6; 5e-5 = 25 sigma flip margin. Smaller tau =
// fewer fixup rows = less W re-streaming (2 MB per active fixup block).
#define FIX_TAU 5e-5f

typedef __attribute__((ext_vector_type(8))) _Float16 half8;
typedef __attribute__((ext_vector_type(4))) float f32x4;

// async global->LDS, 16 B per lane; lds base wave-uniform, data lands at
// lds + lane*16 (m104/m108).
static __device__ __forceinline__ void ld_g2l16(const void* g, void* l) {
  __builtin_amdgcn_global_load_lds(
      (const __attribute__((address_space(1))) void*)g,
      (__attribute__((address_space(3))) void*)l, 16, 0, 0);
}

// ---------------------------------------------------------------------------
// Pass 0: split Wq,Wk into f16 hi (2-pairing GEMM: A hi/lo x B hi),
// fragment-chunk order: chunk c = (kt*32 + ct)*64 + kblk*16 + n holds
// W[e = ct*16+n][d = kt*32 + kblk*8 .. +8]. Also zero-inits accumulators.
// This order makes a lane's B-fragment a contiguous 16 B global load.
// ---------------------------------------------------------------------------
__global__ __launch_bounds__(256) void wsplit(
    const float* __restrict__ Wq, const float* __restrict__ Wk,
    _Float16* __restrict__ wqh, _Float16* __restrict__ wkh,
    float* __restrict__ ssk, float* __restrict__ ssq,
    float* __restrict__ dotb, int* __restrict__ fixcnt) {
  const int t = blockIdx.x * 256 + threadIdx.x;  // 0..65535
  if (t == 0) *fixcnt = 0;
  ssk[t] = 0.0f;
  ssq[t] = 0.0f;
  dotb[t] = 0.0f;

  const int m = t >> 15;         // 0 = Wq, 1 = Wk
  const int c = t & 32767;       // chunk id
  const int kt = c >> 11;
  const int ct = (c >> 6) & 31;
  const int l = c & 63;
  const int n = l & 15;
  const int kblk = l >> 4;
  const int e = ct * 16 + n;
  const int d0 = kt * 32 + kblk * 8;
  const float* src = (m ? Wk : Wq) + (long)e * 512 + d0;
  _Float16* dh = (m ? wkh : wqh) + (long)c * 8;
  float4 v0 = *(const float4*)src;
  float4 v1 = *(const float4*)(src + 4);
  float av[8] = {v0.x, v0.y, v0.z, v0.w, v1.x, v1.y, v1.z, v1.w};
  half8 hi;
#pragma unroll
  for (int j = 0; j < 8; ++j) hi[j] = (_Float16)av[j];
  *(half8*)dh = hi;
}

// ---------------------------------------------------------------------------
// FUSED GEMM: q = x*Wq^T and k = x*Wk^T. 128x128 tile, BK=32, 4 waves 2x2,
// 2-pairing f16 split (ah*bh + al*bh). LDS-traffic-minimized structure:
//  - A: raw f32 x-tile staged via global_load_lds (no CONV ds_writes, no
//    f32 prefetch regs). XOR-swizzle byte^=(row&7)<<4 applied on the global
//    SOURCE address (linear LDS dest, rule: both-sides-or-neither) and on
//    the ds_read address -> <=2-way bank conflicts. hi/lo split done by
//    VALU at read time.
//  - B: NEVER in LDS. One persistent register set bq[4]/bk[4]; each frag
//    reloaded (global, L2-resident, coalesced 16 B/lane) right after its
//    last MFMA use of the step -> ~400 cyc cover for ~300 cyc L2 latency.
//  - Barrier: vmcnt(8) drains the 4 A-g2l (oldest) only; the 8 B reloads
//    stay in flight across the barrier. lgkmcnt(0) protects A-buf WAR.
// LDS pipe/CU/kt drops ~2176 -> ~1024 cyc vs 640 MFMA -> ceiling ~60%.
// ---------------------------------------------------------------------------
__global__ __launch_bounds__(256, 2) void gemm_fused(
    const float* __restrict__ x,
    const _Float16* __restrict__ wqh, const _Float16* __restrict__ wkh,
    float* __restrict__ ssqOut, float* __restrict__ sskOut,
    float* __restrict__ dotOut,
    float* __restrict__ qedge, float* __restrict__ kedge) {
  __shared__ float smemf[8704];  // 34816 B (= epilogue KX 128*136 halfs)
  float* A0 = smemf;             // 16 KB: 128 rows x 32 f32, swizzled
  float* A1 = smemf + 4096;

  const int tid = threadIdx.x;
  const int lane = tid & 63;
  const int w = tid >> 6;
  const int wrow = w & 1, wcol = w >> 1;
  const int g = lane >> 4, n = lane & 15;
  const int bx0 = blockIdx.x;
  const int bx = ((bx0 & 7) << 8) | (bx0 >> 3);  // XCD-contiguous (2048 = 8*256)
  const int rb = bx >> 2, cb = bx & 3;
  const long r0 = (long)rb * 128;

  // ---- A staging map (g2l, linear dest, inverse-swizzled source) ----
  // call j of wave w writes phys bytes [(w*4+j)*1024, +1024), lane*16 each.
  // phys -> row = w*32 + j*8 + (lane>>3); kb_phys = (lane&7)*16;
  // logical col = kb_phys ^ ((row&7)<<4), row&7 = lane>>3.
  const int srow = w * 32 + (lane >> 3);                  // + j*8
  const int scol = (((lane & 7) ^ (lane >> 3)) << 2);     // float index
  const float* gsrc = x + (r0 + srow) * 512 + scol;       // + j*4096 + kt*32

  // ---- A read map: row(mb) = wrow*64 + mb*16 + (lane&15); row&7 = lane&7;
  // frag = logical floats [kb0/4 .. +8), kb0 = (lane>>4)*32 bytes.
  const int sw = (lane & 7) << 4;
  const int kb0 = (lane >> 4) << 5;
  const int o1 = kb0 ^ sw;           // byte offset within row, piece 1
  const int o2 = (kb0 + 16) ^ sw;    // piece 2
  const int rdrow0 = wrow * 64 + (lane & 15);

  // ---- B fragment bases (fragment-chunk order; 16 B per lane) ----
  const _Float16* bqb = wqh + ((long)((cb * 8 + wcol * 4) * 64 + lane)) * 8;
  const _Float16* bkb = wkh + ((long)((cb * 8 + wcol * 4) * 64 + lane)) * 8;

  f32x4 accq[4][4], acck[4][4];
#pragma unroll
  for (int mb = 0; mb < 4; ++mb)
#pragma unroll
    for (int nb = 0; nb < 4; ++nb) {
      accq[mb][nb] = (f32x4){0.f, 0.f, 0.f, 0.f};
      acck[mb][nb] = (f32x4){0.f, 0.f, 0.f, 0.f};
    }

  half8 bq[4], bk[4];  // persistent single B set

#define STAGE_A(ktv, AB_)                                                 \
  do {                                                                    \
    _Pragma("unroll") for (int j = 0; j < 4; ++j)                         \
        ld_g2l16(gsrc + j * 4096 + (ktv) * 32,                            \
                 (char*)(AB_) + (w * 4 + j) * 1024);                      \
  } while (0)

#define LOAD_B_ALL(ktv)                                                   \
  do {                                                                    \
    _Pragma("unroll") for (int nb = 0; nb < 4; ++nb) {                    \
      bq[nb] = *(const half8*)(bqb + (long)(ktv)*16384 + nb * 512);       \
      bk[nb] = *(const half8*)(bkb + (long)(ktv)*16384 + nb * 512);       \
    }                                                                     \
  } while (0)

  // COMPUTE: read+convert A frags, 64 MFMA; after each nb-group's last use,
  // reload bq[nb]/bk[nb] for K-step KTN.
#define COMPUTE(AB_, KTN)                                                 \
  do {                                                                    \
    half8 ah[4], al[4];                                                   \
    _Pragma("unroll") for (int mb = 0; mb < 4; ++mb) {                    \
      const char* rp = (const char*)((AB_) + (rdrow0 + mb * 16) * 32);    \
      float4 v0 = *(const float4*)(rp + o1);                              \
      float4 v1 = *(const float4*)(rp + o2);                              \
      float av[8] = {v0.x, v0.y, v0.z, v0.w, v1.x, v1.y, v1.z, v1.w};     \
      half8 h, lo;                                                        \
      _Pragma("unroll") for (int j = 0; j < 8; ++j) {                     \
        _Float16 a = (_Float16)av[j];                                     \
        h[j] = a;                                                         \
        lo[j] = (_Float16)(av[j] - (float)a);                             \
      }                                                                   \
      ah[mb] = h;                                                         \
      al[mb] = lo;                                                        \
    }                                                                     \
    _Pragma("unroll") for (int nb = 0; nb < 4; ++nb) {                    \
      __builtin_amdgcn_s_setprio(1);                                      \
      _Pragma("unroll") for (int mb = 0; mb < 4; ++mb) {                  \
        accq[mb][nb] = __builtin_amdgcn_mfma_f32_16x16x32_f16(            \
            ah[mb], bq[nb], accq[mb][nb], 0, 0, 0);                       \
        acck[mb][nb] = __builtin_amdgcn_mfma_f32_16x16x32_f16(            \
            ah[mb], bk[nb], acck[mb][nb], 0, 0, 0);                       \
        accq[mb][nb] = __builtin_amdgcn_mfma_f32_16x16x32_f16(            \
            al[mb], bq[nb], accq[mb][nb], 0, 0, 0);                       \
        acck[mb][nb] = __builtin_amdgcn_mfma_f32_16x16x32_f16(            \
            al[mb], bk[nb], acck[mb][nb], 0, 0, 0);                       \
      }                                                                   \
      __builtin_amdgcn_s_setprio(0);                                      \
      bq[nb] = *(const half8*)(bqb + (long)(KTN)*16384 + nb * 512);       \
      bk[nb] = *(const half8*)(bkb + (long)(KTN)*16384 + nb * 512);       \
    }                                                                     \
  } while (0)

  // counted barrier: drain MY 4 A-g2l (oldest vmem), leave the 8 B reloads
  // in flight; lgkmcnt(0) orders ds_reads of cur buf before it's re-staged.
#define BARRIER_CNT()                                       \
  do {                                                      \
    asm volatile("s_waitcnt vmcnt(8)" ::: "memory");        \
    asm volatile("s_waitcnt lgkmcnt(0)" ::: "memory");      \
    __builtin_amdgcn_sched_barrier(0);                      \
    __builtin_amdgcn_s_barrier();                           \
  } while (0)

#define FENCE() __builtin_amdgcn_sched_barrier(0)

  // ---- prologue: A(0) g2l (oldest), B(0) -> regs ----
  STAGE_A(0, A0);
  FENCE();
  LOAD_B_ALL(0);
  FENCE();
  BARRIER_CNT();  // A(0) staged; B(0) in flight (waited at first MFMA use)

  for (int i = 0; i < 8; ++i) {
    const int kt = 2 * i;
    // even step kt: compute A0 + B(kt); stage A(kt+1)->A1; reload B->kt+1
    STAGE_A(kt + 1, A1);
    FENCE();
    COMPUTE(A0, kt + 1);
    BARRIER_CNT();
    // odd step kt+1: compute A1 + B(kt+1); stage A(kt+2)->A0; reload B->kt+2
    {
      const int ktn = (kt + 2 < 16) ? (kt + 2) : 15;  // dummy on last iter
      STAGE_A(ktn, A0);
      FENCE();
      COMPUTE(A1, ktn);
    }
    BARRIER_CNT();
  }

  // drain all vmem (dummy g2l targets A0, which overlaps epilogue KX).
  asm volatile("s_waitcnt vmcnt(0)" ::: "memory");
  __builtin_amdgcn_sched_barrier(0);
  __syncthreads();

  // ---------------- epilogue ----------------
  // k-acc -> LDS (f16), row-major stride 136 halfs (=272 B) so the 4 g-rows
  // of a read/write group land on different banks. 128*136*2 B = 34816 B.
  _Float16* KX = (_Float16*)smemf;
  const int col0 = wcol * 64 + n;
  const int rbase = wrow * 64;
#pragma unroll
  for (int mb = 0; mb < 4; ++mb)
#pragma unroll
    for (int reg = 0; reg < 4; ++reg) {
      const int rl = rbase + mb * 16 + g * 4 + reg;
#pragma unroll
      for (int nb = 0; nb < 4; ++nb)
        KX[rl * 136 + col0 + nb * 16] = (_Float16)acck[mb][nb][reg];
    }
  __syncthreads();

  // block-boundary edges: k local row 127 and q local row 0 (f32, 128 cols
  // per (rb,cb) block -> full 512 cols per rb across cb).
  if (wrow == 1 && g == 3) {
#pragma unroll
    for (int nb = 0; nb < 4; ++nb)
      kedge[rb * 512 + cb * 128 + col0 + nb * 16] = acck[3][nb][3];
  }
  if (wrow == 0 && g == 0) {
#pragma unroll
    for (int nb = 0; nb < 4; ++nb)
      qedge[rb * 512 + cb * 128 + col0 + nb * 16] = accq[0][nb][0];
  }

  // per-row partials: ssq, ssk, dot = q[r] . k[r-1] (k from LDS, f16).
  // Local row 0's dot comes from edgedot.
#pragma unroll
  for (int mb = 0; mb < 4; ++mb) {
#pragma unroll
    for (int reg = 0; reg < 4; ++reg) {
      const int rl = rbase + mb * 16 + g * 4 + reg;
      const long row = r0 + rl;
      float sq = 0.f, sk = 0.f, dt = 0.f;
#pragma unroll
      for (int nb = 0; nb < 4; ++nb) {
        float qv = accq[mb][nb][reg];
        float kv = acck[mb][nb][reg];
        sq = fmaf(qv, qv, sq);
        sk = fmaf(kv, kv, sk);
        if (rl > 0) {
          float kp = (float)KX[(rl - 1) * 136 + col0 + nb * 16];
          dt = fmaf(qv, kp, dt);
        }
      }
#pragma unroll
      for (int m = 1; m < 16; m <<= 1) {
        sq += __shfl_xor(sq, m, 64);
        sk += __shfl_xor(sk, m, 64);
        dt += __shfl_xor(dt, m, 64);
      }
      if (n == 0) {
        atomicAdd(&ssqOut[row], sq);
        atomicAdd(&sskOut[row], sk);
        if (rl > 0) atomicAdd(&dotOut[row], dt);
      }
    }
  }
#undef STAGE_A
#undef LOAD_B_ALL
#undef COMPUTE
#undef BARRIER_CNT
#undef FENCE
}

// ---------------------------------------------------------------------------
// Boundary rows (r multiple of 128, r's l != 0): dot = qedge[rb] . kedge[rb-1]
// over all 512 cols. Sole writer of dotOut for these rows.
// ---------------------------------------------------------------------------
__global__ __launch_bounds__(64) void edgedot(
    const float* __restrict__ qedge, const float* __restrict__ kedge,
    float* __restrict__ dotOut) {
  const int rb = blockIdx.x;  // 0..511
  if (rb == 0) return;
  const long row = (long)rb * 128;
  if ((row & (LL - 1)) == 0) return;  // l == 0: p forced to 1, dot unused
  const int lane = threadIdx.x;
  float dt = 0.f;
#pragma unroll
  for (int c = lane; c < 512; c += 64)
    dt = fmaf(qedge[rb * 512 + c], kedge[(rb - 1) * 512 + c], dt);
#pragma unroll
  for (int m = 1; m < 64; m <<= 1) dt += __shfl_xor(dt, m, 64);
  if (lane == 0) dotOut[row] = dt;
}

// ---------------------------------------------------------------------------
// Combine: cos from partials -> p, b_hard, fixlist.
// ---------------------------------------------------------------------------
__global__ __launch_bounds__(256) void combine(
    const float* __restrict__ ssq, const float* __restrict__ ssk,
    const float* __restrict__ dotb, float* __restrict__ dout,
    int* __restrict__ fixlist, int* __restrict__ fixcnt) {
  const int r = blockIdx.x * 256 + threadIdx.x;
  const int l = r & (LL - 1);
  float p;
  float cosv = 0.0f;
  if (l != 0) {
    float nq = fmaxf(sqrtf(ssq[r]), 1e-12f);
    float nk = fmaxf(sqrtf(ssk[r - 1]), 1e-12f);
    cosv = dotb[r] / (nq * nk);
    p = fminf(fmaxf(0.5f * (1.0f - cosv), 0.0f), 1.0f);
  } else {
    p = 1.0f;
  }
  dout[OUT_P + r] = p;
  dout[OUT_BHARD + r] = (p >= 0.5f) ? 1.0f : 0.0f;
  if (l != 0 && fabsf(cosv) < FIX_TAU) {
    int idx = atomicAdd(fixcnt, 1);
    if (idx < FIX_CAP) fixlist[idx] = r;
  }
}

// ---------------------------------------------------------------------------
// f64 recompute of borderline rows (expected ~60 rows at TAU=5e-5).
// ---------------------------------------------------------------------------
__global__ __launch_bounds__(256) void fixup(
    const float* __restrict__ x, const float* __restrict__ Wq,
    const float* __restrict__ Wk, float* __restrict__ dout,
    const int* __restrict__ fixlist, const int* __restrict__ fixcnt) {
  __shared__ float xr[512], xp[512];
  __shared__ double red[3][256];
  const int t = threadIdx.x;
  int nfix = *fixcnt;
  if (nfix > FIX_CAP) nfix = FIX_CAP;

  for (int idx = blockIdx.x; idx < nfix; idx += gridDim.x) {
    const int r = fixlist[idx];
    for (int d = t; d < 512; d += 256) {
      xr[d] = x[(long)r * 512 + d];
      xp[d] = x[(long)(r - 1) * 512 + d];
    }
    __syncthreads();
    double ssq = 0.0, ssk = 0.0, dot = 0.0;
    for (int e = t; e < 512; e += 256) {
      const float* wq = Wq + (long)e * 512;
      const float* wk = Wk + (long)e * 512;
      double q = 0.0, k = 0.0;
      for (int d = 0; d < 512; ++d) {
        q = fma((double)xr[d], (double)wq[d], q);
        k = fma((double)xp[d], (double)wk[d], k);
      }
      ssq += q * q;
      ssk += k * k;
      dot += q * k;
    }
    red[0][t] = ssq;
    red[1][t] = ssk;
    red[2][t] = dot;
    __syncthreads();
    for (int s = 128; s > 0; s >>= 1) {
      if (t < s) {
        red[0][t] += red[0][t + s];
        red[1][t] += red[1][t + s];
        red[2][t] += red[2][t + s];
      }
      __syncthreads();
    }
    if (t == 0) {
      double nq = sqrt(red[0][0]);
      double nk = sqrt(red[1][0]);
      if (nq < 1e-12) nq = 1e-12;
      if (nk < 1e-12) nk = 1e-12;
      float c = (float)(red[2][0] / (nq * nk));
      float p = fminf(fmaxf(0.5f * (1.0f - c), 0.0f), 1.0f);
      dout[OUT_P + r] = p;
      dout[OUT_BHARD + r] = (p >= 0.5f) ? 1.0f : 0.0f;
    }
    __syncthreads();
  }
}

// ---------------------------------------------------------------------------
// Per-batch scan (shfl-based), mask, p_compressed, sel, counts.
// ---------------------------------------------------------------------------
__global__ __launch_bounds__(256) void scanb(
    float* __restrict__ dout, int* __restrict__ sel,
    int* __restrict__ counts, float* __restrict__ sump) {
  __shared__ int wtot[4];
  __shared__ float wps[4];
  const int b = blockIdx.x;
  const int t = threadIdx.x;
  const int lane = t & 63, wv = t >> 6;
  const long base = (long)b * LL;

  int cnt = 0;
  float psum = 0.0f;
#pragma unroll 4
  for (int j = 0; j < 32; ++j) {
    int l = t * 32 + j;
    float bh = dout[OUT_BHARD + base + l];
    float pv = dout[OUT_P + base + l];
    cnt += (bh > 0.5f) ? 1 : 0;
    psum += pv;
  }
  int inc = cnt;
#pragma unroll
  for (int off = 1; off < 64; off <<= 1) {
    int u = __shfl_up(inc, off, 64);
    if (lane >= off) inc += u;
  }
  float ps = psum;
#pragma unroll
  for (int off = 1; off < 64; off <<= 1) ps += __shfl_xor(ps, off, 64);
  if (lane == 63) wtot[wv] = inc;
  if (lane == 0) wps[wv] = ps;
  __syncthreads();
  int wbase = 0, total = 0;
#pragma unroll
  for (int i = 0; i < 4; ++i) {
    int c = wtot[i];
    if (i < wv) wbase += c;
    total += c;
  }
  if (t == 0) {
    counts[b] = total;
    sump[b] = wps[0] + wps[1] + wps[2] + wps[3];
  }
  for (int j = 0; j < 32; ++j) {
    int l = t * 32 + j;
    dout[OUT_MASK + base + l] = (l < total) ? 1.0f : 0.0f;
    dout[OUT_PCOMP + base + l] = 0.0f;
  }
  __syncthreads();
  int pos = wbase + inc - cnt;  // exclusive prefix
  for (int j = 0; j < 32; ++j) {
    int l = t * 32 + j;
    float bh = dout[OUT_BHARD + base + l];
    if (bh > 0.5f) {
      dout[OUT_PCOMP + base + pos] = dout[OUT_P + base + l];
      sel[base + pos] = l;
      ++pos;
    }
  }
}

// ---------------------------------------------------------------------------
__global__ void lossk(float* __restrict__ dout, const int* __restrict__ counts,
                      const float* __restrict__ sump) {
  if (threadIdx.x == 0 && blockIdx.x == 0) {
    float fc = 0.0f, gs = 0.0f;
    for (int b = 0; b < BB; ++b) {
      fc += (float)counts[b];
      gs += sump[b];
    }
    float F = fc / (float)NROWS;
    float G = gs / (float)NROWS;
    dout[OUT_LOSS] = 1.2f * (5.0f * F * G + (1.0f - F) * (1.0f - G));
  }
}

// ---------------------------------------------------------------------------
__global__ __launch_bounds__(128) void emit(
    const float* __restrict__ x, float* __restrict__ dout,
    const int* __restrict__ sel, const int* __restrict__ counts) {
  const long bid = blockIdx.x;
  const int b = (int)(bid >> 13);
  const int j = (int)(bid & (LL - 1));
  const int cnt = counts[b];
  float4 v = make_float4(0.0f, 0.0f, 0.0f, 0.0f);
  if (j < cnt) {
    const int l = sel[((long)b << 13) + j];
    v = *(const float4*)(x + (((long)b << 13) + l) * 512 + threadIdx.x * 4);
  }
  *(float4*)(dout + OUT_COMP + (((long)b << 13) + j) * 512 + threadIdx.x * 4) = v;
}

// ---------------------------------------------------------------------------
extern "C" void kernel_launch(void* const* d_in, const int* in_sizes, int n_in,
                              void* d_out, int out_size, void* d_ws,
                              size_t ws_size, hipStream_t stream) {
  const float* x = (const float*)d_in[0];
  const float* Wq = (const float*)d_in[1];
  const float* Wk = (const float*)d_in[2];
  float* out = (float*)d_out;
  char* ws = (char*)d_ws;

  int* fixlist = (int*)(ws + WS_FIXLIST);
  int* fixcnt = (int*)(ws + WS_FIXCNT);
  int* counts = (int*)(ws + WS_COUNTS);
  float* sump = (float*)(ws + WS_SUMP);
  int* sel = (int*)(ws + WS_SEL);
  float* ssk = (float*)(ws + WS_SSK);
  float* ssq = (float*)(ws + WS_SSQ);
  float* dotb = (float*)(ws + WS_DOT);
  _Float16* wqh = (_Float16*)(ws + WS_WQH);
  _Float16* wkh = (_Float16*)(ws + WS_WKH);

  // edge buffers (512x512 f32 each = 1 MB) staged in d_out's compressed
  // region; emit overwrites it at the end.
  float* kedge = (float*)(out + OUT_COMP);
  float* qedge = (float*)(out + OUT_COMP + 262144);

  wsplit<<<256, 256, 0, stream>>>(Wq, Wk, wqh, wkh, ssk, ssq, dotb, fixcnt);
  gemm_fused<<<2048, 256, 0, stream>>>(x, wqh, wkh, ssq, ssk, dotb, qedge, kedge);
  edgedot<<<512, 64, 0, stream>>>(qedge, kedge, dotb);
  combine<<<NROWS / 256, 256, 0, stream>>>(ssq, ssk, dotb, out, fixlist, fixcnt);
  fixup<<<512, 256, 0, stream>>>(x, Wq, Wk, out, fixlist, fixcnt);
  scanb<<<BB, 256, 0, stream>>>(out, sel, counts, sump);
  lossk<<<1, 64, 0, stream>>>(out, counts, sump);
  emit<<<NROWS, 128, 0, stream>>>(x, out, sel, counts);
}